// Round 6
// baseline (1324.777 us; speedup 1.0000x reference)
//
#include <hip/hip_runtime.h>
#include <cmath>

#define N_NODES 50000
#define N_EDGES 100000
#define HALF_N  25000
#define DIM     256
#define NDEPTH  2
#define MAXDEG  64

// per-layer weight-buffer offsets (bf16 elements), chunk-packed layouts
#define WT_QKVE 0          // 8 tiles x [64 k8][128 n] bf16x8  (k/v interleaved cols)
#define WT_WO   524288     // 2 tiles x [32 k8][128 n]
#define WT_W1   589824     // 8 chunks x [32 k8][128 n]
#define WT_W2   851968     // 8 chunks x [16 k8][256 n]
#define WT_LAYER 1114112

typedef __bf16 bf16;
typedef bf16 bf16x8 __attribute__((ext_vector_type(8)));
typedef bf16 bf16x4 __attribute__((ext_vector_type(4)));
typedef float f32x4 __attribute__((ext_vector_type(4)));

__device__ __forceinline__ float wave_sum(float v) {
  v += __shfl_xor(v, 1);
  v += __shfl_xor(v, 2);
  v += __shfl_xor(v, 4);
  v += __shfl_xor(v, 8);
  v += __shfl_xor(v, 16);
  v += __shfl_xor(v, 32);
  return v;
}

// exact-GELU via A&S 7.1.26 erf (abs err ~1.5e-7)
__device__ __forceinline__ float fast_gelu(float v) {
  float ax = fabsf(v) * 0.70710678118654752f;
  float t = __builtin_amdgcn_rcpf(fmaf(0.3275911f, ax, 1.0f));
  float p = t * fmaf(t, fmaf(t, fmaf(t, fmaf(t, 1.061405429f, -1.453152027f),
                                     1.421413741f), -0.284496736f), 0.254829592f);
  float e = __expf(-ax * ax);
  float erfv = fmaf(-p, e, 1.0f);
  float ph = copysignf(erfv, v);
  return 0.5f * v * (1.0f + ph);
}

// ---------------- layer-0 LN1: x -> A2 left half (stride 512) ----------------
__global__ void ln0_kernel(const float* __restrict__ in, const float* __restrict__ g,
                           const float* __restrict__ b, bf16* __restrict__ A2) {
  int row = blockIdx.x * 4 + (threadIdx.x >> 6);
  if (row >= HALF_N) return;
  int lane = threadIdx.x & 63;
  float4 x = reinterpret_cast<const float4*>(in + (size_t)row * DIM)[lane];
  float mu = wave_sum(x.x + x.y + x.z + x.w) * (1.0f / DIM);
  float d0 = x.x - mu, d1 = x.y - mu, d2 = x.z - mu, d3 = x.w - mu;
  float var = wave_sum(d0*d0 + d1*d1 + d2*d2 + d3*d3) * (1.0f / DIM);
  float r = rsqrtf(var + 1e-5f);
  float4 gv = reinterpret_cast<const float4*>(g)[lane];
  float4 bv = reinterpret_cast<const float4*>(b)[lane];
  bf16x4 o;
  o[0] = (bf16)(d0 * r * gv.x + bv.x);
  o[1] = (bf16)(d1 * r * gv.y + bv.y);
  o[2] = (bf16)(d2 * r * gv.z + bv.z);
  o[3] = (bf16)(d3 * r * gv.w + bv.w);
  *reinterpret_cast<bf16x4*>(A2 + (size_t)row * 512 + lane * 4) = o;
}

// ---------------- N-loop MFMA GEMM (qkve): A-frags in regs, W prefetch -------
// A [M][KK] bf16; Wp chunk-packed [NJ][KK/8][128] bf16x8; C [M][NJ*128] bf16.
template<int KK, int NJ>
__global__ __launch_bounds__(256, 6) void gemm_nloop(
    const bf16* __restrict__ A, const bf16* __restrict__ Wp,
    const float* __restrict__ bias, bf16* __restrict__ C, int M) {
  constexpr int STEPS = KK / 64;
  constexpr int KI = KK / 32;          // per-lane k8 indices (k8 = t*4 + kb)
  __shared__ bf16x8 Bs[1024];          // 16 KB; Cs (64x128 bf16) aliases
  const int tid = threadIdx.x;
  const int lane = tid & 63, wv = tid >> 6;
  const int wr = wv >> 1, wc = wv & 1;
  const int lm = lane & 15, kb = (lane >> 4) & 3;
  const int row0 = blockIdx.x * 64;
  const bf16x8* Wp8 = reinterpret_cast<const bf16x8*>(Wp);
  bf16x8 pf[4];
  auto ldpf = [&](int p) {
    int jn = p / STEPS, st = p % STEPS;
    const bf16x8* src = Wp8 + (size_t)jn * (KK * 16) + st * 1024;
#pragma unroll
    for (int i = 0; i < 4; ++i) pf[i] = src[tid + i * 256];
  };
  ldpf(0);
  // A fragments direct to regs: lane covers its own rows
  bf16x8 afr[2][KI];
#pragma unroll
  for (int mi = 0; mi < 2; ++mi) {
    int row = row0 + wr * 32 + mi * 16 + lm;
    if (row >= M) row = M - 1;
    const bf16* pa = A + (size_t)row * KK + kb * 8;
#pragma unroll
    for (int t = 0; t < KI; ++t)
      afr[mi][t] = *reinterpret_cast<const bf16x8*>(pa + t * 32);
  }
  for (int jn = 0; jn < NJ; ++jn) {
    f32x4 acc[2][4] = {};
    for (int st = 0; st < STEPS; ++st) {
      __syncthreads();
#pragma unroll
      for (int i = 0; i < 4; ++i) Bs[tid + i * 256] = pf[i];
      __syncthreads();
      int p = jn * STEPS + st + 1;
      if (p < NJ * STEPS) ldpf(p);
#pragma unroll
      for (int ks = 0; ks < 2; ++ks) {
        bf16x8 bfr[4];
#pragma unroll
        for (int ni = 0; ni < 4; ++ni)
          bfr[ni] = Bs[(ks * 4 + kb) * 128 + wc * 64 + ni * 16 + lm];
#pragma unroll
        for (int mi = 0; mi < 2; ++mi)
#pragma unroll
          for (int ni = 0; ni < 4; ++ni)
            acc[mi][ni] = __builtin_amdgcn_mfma_f32_16x16x32_bf16(afr[mi][st * 2 + ks], bfr[ni], acc[mi][ni], 0, 0, 0);
      }
    }
    __syncthreads();
    bf16* Cs = (bf16*)Bs;
#pragma unroll
    for (int ni = 0; ni < 4; ++ni) {
      int c = wc * 64 + ni * 16 + lm;
      float bval = bias[jn * 128 + c];
#pragma unroll
      for (int mi = 0; mi < 2; ++mi)
#pragma unroll
        for (int e = 0; e < 4; ++e) {
          int r = wr * 32 + mi * 16 + kb * 4 + e;
          Cs[r * 128 + c] = (bf16)(acc[mi][ni][e] + bval);
        }
    }
    __syncthreads();
    bf16x8* C8 = reinterpret_cast<bf16x8*>(C);
    const bf16x8* Cs8 = (const bf16x8*)Bs;
#pragma unroll
    for (int i = 0; i < 4; ++i) {
      int idx = tid + i * 256;
      int row = idx >> 4, c8 = idx & 15;
      int grow = row0 + row;
      if (grow < M) C8[(size_t)grow * (NJ * 16) + jn * 16 + c8] = Cs8[row * 16 + c8];
    }
  }
}

// ---------------- Wo GEMM fused with gr1 + LN2 (lower rows) ------------------
__global__ __launch_bounds__(256, 6) void wo_fused(
    const bf16* __restrict__ A, const bf16* __restrict__ Wp,
    const float* __restrict__ bo, const float* __restrict__ gattn,
    const float* __restrict__ ln2g, const float* __restrict__ ln2b,
    float* __restrict__ nodes, bf16* __restrict__ xn, int M) {
  __shared__ bf16x8 Bs[1024];          // 16 KB
  __shared__ bf16 Cs[64 * 256];        // 32 KB, XOR-swizzled chunks
  const int tid = threadIdx.x;
  const int lane = tid & 63, wv = tid >> 6;
  const int wr = wv >> 1, wc = wv & 1;
  const int lm = lane & 15, kb = (lane >> 4) & 3;
  const int row0 = blockIdx.x * 64;
  const bf16x8* Wp8 = (const bf16x8*)Wp;
  bf16x8 pf[4];
  auto ldpf = [&](int p) {
    const bf16x8* src = Wp8 + (p >> 2) * 4096 + (p & 3) * 1024;
#pragma unroll
    for (int i = 0; i < 4; ++i) pf[i] = src[tid + i * 256];
  };
  ldpf(0);
  bf16x8 afr[2][8];
#pragma unroll
  for (int mi = 0; mi < 2; ++mi) {
    int row = row0 + wr * 32 + mi * 16 + lm;
    if (row >= M) row = M - 1;
    const bf16* pa = A + (size_t)row * 256 + kb * 8;
#pragma unroll
    for (int t = 0; t < 8; ++t)
      afr[mi][t] = *reinterpret_cast<const bf16x8*>(pa + t * 32);
  }
  for (int jn = 0; jn < 2; ++jn) {
    f32x4 acc[2][4] = {};
    for (int st = 0; st < 4; ++st) {
      __syncthreads();
#pragma unroll
      for (int i = 0; i < 4; ++i) Bs[tid + i * 256] = pf[i];
      __syncthreads();
      int p = jn * 4 + st + 1;
      if (p < 8) ldpf(p);
#pragma unroll
      for (int ks = 0; ks < 2; ++ks) {
        bf16x8 bfr[4];
#pragma unroll
        for (int ni = 0; ni < 4; ++ni)
          bfr[ni] = Bs[(ks * 4 + kb) * 128 + wc * 64 + ni * 16 + lm];
#pragma unroll
        for (int mi = 0; mi < 2; ++mi)
#pragma unroll
          for (int ni = 0; ni < 4; ++ni)
            acc[mi][ni] = __builtin_amdgcn_mfma_f32_16x16x32_bf16(afr[mi][st * 2 + ks], bfr[ni], acc[mi][ni], 0, 0, 0);
      }
    }
#pragma unroll
    for (int ni = 0; ni < 4; ++ni) {
      int cfull = jn * 128 + wc * 64 + ni * 16 + lm;
      float bval = bo[cfull];
#pragma unroll
      for (int mi = 0; mi < 2; ++mi)
#pragma unroll
        for (int e = 0; e < 4; ++e) {
          int r = wr * 32 + mi * 16 + kb * 4 + e;
          int ch = (cfull >> 3) ^ (r & 7);
          Cs[r * 256 + ch * 8 + (cfull & 7)] = (bf16)(acc[mi][ni][e] + bval);
        }
    }
  }
  __syncthreads();
  // fused gr1 + LN2: wave per row (coalesced float4 on nodes)
  for (int pass = 0; pass < 16; ++pass) {
    int r = pass * 4 + wv;
    int grow = row0 + r;
    if (grow >= M) continue;
    int ch = (lane >> 1) ^ (r & 7);
    bf16x4 c4 = *reinterpret_cast<const bf16x4*>(Cs + r * 256 + ch * 8 + (lane & 1) * 4);
    float x0 = (float)c4[0], x1 = (float)c4[1], x2 = (float)c4[2], x3 = (float)c4[3];
    float4 rv = reinterpret_cast<const float4*>(nodes + (size_t)grow * 256)[lane];
    float4 w0 = reinterpret_cast<const float4*>(gattn)[lane];
    float4 w1 = reinterpret_cast<const float4*>(gattn + 256)[lane];
    float4 w2 = reinterpret_cast<const float4*>(gattn + 512)[lane];
    float dot = x0 * (w0.x + w2.x) + rv.x * (w1.x - w2.x)
              + x1 * (w0.y + w2.y) + rv.y * (w1.y - w2.y)
              + x2 * (w0.z + w2.z) + rv.z * (w1.z - w2.z)
              + x3 * (w0.w + w2.w) + rv.w * (w1.w - w2.w);
    dot = wave_sum(dot);
    float gate = 1.0f / (1.0f + __expf(-dot));
    float n0 = fmaf(x0 - rv.x, gate, rv.x);
    float n1 = fmaf(x1 - rv.y, gate, rv.y);
    float n2 = fmaf(x2 - rv.z, gate, rv.z);
    float n3 = fmaf(x3 - rv.w, gate, rv.w);
    float4 o; o.x = n0; o.y = n1; o.z = n2; o.w = n3;
    reinterpret_cast<float4*>(nodes + (size_t)grow * 256)[lane] = o;
    float mu = wave_sum(n0 + n1 + n2 + n3) * (1.0f / DIM);
    float d0 = n0 - mu, d1 = n1 - mu, d2 = n2 - mu, d3 = n3 - mu;
    float var = wave_sum(d0*d0 + d1*d1 + d2*d2 + d3*d3) * (1.0f / DIM);
    float rs = rsqrtf(var + 1e-5f);
    float4 gv = reinterpret_cast<const float4*>(ln2g)[lane];
    float4 bv = reinterpret_cast<const float4*>(ln2b)[lane];
    bf16x4 ob;
    ob[0] = (bf16)(d0 * rs * gv.x + bv.x);
    ob[1] = (bf16)(d1 * rs * gv.y + bv.y);
    ob[2] = (bf16)(d2 * rs * gv.z + bv.z);
    ob[3] = (bf16)(d3 * rs * gv.w + bv.w);
    *reinterpret_cast<bf16x4*>(xn + (size_t)grow * 256 + lane * 4) = ob;
  }
}

// ---------------- fused FF + gr2 (+LN1next | +out-proj), 64-row panel --------
// A-frags in regs; LDS = Bs 32 KB + Hs 16 KB = 48 KB -> 3 blocks/CU.
template<int LAST>
__global__ __launch_bounds__(512, 6) void ff_fused(
    const bf16* __restrict__ A, const bf16* __restrict__ W1p,
    const float* __restrict__ b1, const bf16* __restrict__ W2p,
    const float* __restrict__ b2, float* __restrict__ nodes,
    const float* __restrict__ gff, const float* __restrict__ ln1g,
    const float* __restrict__ ln1b, bf16* __restrict__ A2,
    const float* __restrict__ Wout, const float* __restrict__ bout,
    float* __restrict__ out, int M) {
  __shared__ bf16x8 Bs[2048];          // 32 KB (Cs aliases)
  __shared__ bf16x8 Hs[1024];          // 16 KB
  const int tid = threadIdx.x;
  const int lane = tid & 63, wv = tid >> 6;
  const int wr = wv >> 2, wc = wv & 3;
  const int lm = lane & 15, kb = (lane >> 4) & 3;
  const int row0 = blockIdx.x * 64;
  const bf16x8* W1p8 = (const bf16x8*)W1p;
  const bf16x8* W2p8 = (const bf16x8*)W2p;
  bf16x8 pf[4];
  auto ldpf = [&](int p) {
    const bf16x8* src = (((p & 3) < 2) ? W1p8 : W2p8) + ((p >> 2) * 4096 + (p & 1) * 2048);
#pragma unroll
    for (int i = 0; i < 4; ++i) pf[i] = src[tid + i * 512];
  };
  ldpf(0);
  bf16x8 afr[2][8];
#pragma unroll
  for (int mi = 0; mi < 2; ++mi) {
    int row = row0 + wr * 32 + mi * 16 + lm;
    if (row >= M) row = M - 1;
    const bf16* pa = A + (size_t)row * 256 + kb * 8;
#pragma unroll
    for (int t = 0; t < 8; ++t)
      afr[mi][t] = *reinterpret_cast<const bf16x8*>(pa + t * 32);
  }
  f32x4 acc[2][4] = {};
  bf16* hsb = (bf16*)Hs;
  for (int j = 0; j < 8; ++j) {
    f32x4 acc1[2][2] = {};
#pragma unroll
    for (int half = 0; half < 2; ++half) {
      __syncthreads();
#pragma unroll
      for (int i = 0; i < 4; ++i) Bs[tid + i * 512] = pf[i];
      __syncthreads();
      ldpf(j * 4 + half + 1);
#pragma unroll
      for (int ks = 0; ks < 4; ++ks) {
        bf16x8 bfr[2];
#pragma unroll
        for (int ni = 0; ni < 2; ++ni)
          bfr[ni] = Bs[(ks * 4 + kb) * 128 + wc * 32 + ni * 16 + lm];
#pragma unroll
        for (int mi = 0; mi < 2; ++mi)
#pragma unroll
          for (int ni = 0; ni < 2; ++ni)
            acc1[mi][ni] = __builtin_amdgcn_mfma_f32_16x16x32_bf16(afr[mi][half * 4 + ks], bfr[ni], acc1[mi][ni], 0, 0, 0);
      }
    }
#pragma unroll
    for (int ni = 0; ni < 2; ++ni) {
      int c = wc * 32 + ni * 16 + lm;
      float bval = b1[j * 128 + c];
#pragma unroll
      for (int mi = 0; mi < 2; ++mi)
#pragma unroll
        for (int e = 0; e < 4; ++e) {
          int r = wr * 32 + mi * 16 + kb * 4 + e;
          float v = fast_gelu(acc1[mi][ni][e] + bval);
          hsb[((c >> 3) * 64 + r) * 8 + (c & 7)] = (bf16)v;
        }
    }
#pragma unroll
    for (int h2 = 0; h2 < 2; ++h2) {
      __syncthreads();
#pragma unroll
      for (int i = 0; i < 4; ++i) Bs[tid + i * 512] = pf[i];
      __syncthreads();
      int p = j * 4 + 2 + h2 + 1;
      if (p < 32) ldpf(p);
#pragma unroll
      for (int ks = 0; ks < 2; ++ks) {
        bf16x8 af[2], bfr[4];
#pragma unroll
        for (int mi = 0; mi < 2; ++mi)
          af[mi] = Hs[(h2 * 8 + ks * 4 + kb) * 64 + wr * 32 + mi * 16 + lm];
#pragma unroll
        for (int ni = 0; ni < 4; ++ni)
          bfr[ni] = Bs[(ks * 4 + kb) * 256 + wc * 64 + ni * 16 + lm];
#pragma unroll
        for (int mi = 0; mi < 2; ++mi)
#pragma unroll
          for (int ni = 0; ni < 4; ++ni)
            acc[mi][ni] = __builtin_amdgcn_mfma_f32_16x16x32_bf16(af[mi], bfr[ni], acc[mi][ni], 0, 0, 0);
      }
    }
  }
  __syncthreads();
  bf16* Cs = (bf16*)Bs;
#pragma unroll
  for (int ni = 0; ni < 4; ++ni) {
    int c = wc * 64 + ni * 16 + lm;
    float bval = b2[c];
#pragma unroll
    for (int mi = 0; mi < 2; ++mi)
#pragma unroll
      for (int e = 0; e < 4; ++e) {
        int r = wr * 32 + mi * 16 + kb * 4 + e;
        int ch = (c >> 3) ^ (r & 7);
        Cs[r * 256 + ch * 8 + (c & 7)] = (bf16)(acc[mi][ni][e] + bval);
      }
  }
  __syncthreads();
  // fused epilogue: wave per row (coalesced)
  for (int pass = 0; pass < 8; ++pass) {
    int r = pass * 8 + wv;
    int grow = row0 + r;
    if (grow >= M) continue;
    int ch = (lane >> 1) ^ (r & 7);
    bf16x4 c4 = *reinterpret_cast<const bf16x4*>(Cs + r * 256 + ch * 8 + (lane & 1) * 4);
    float x0 = (float)c4[0], x1 = (float)c4[1], x2 = (float)c4[2], x3 = (float)c4[3];
    float4 rv = reinterpret_cast<const float4*>(nodes + (size_t)grow * 256)[lane];
    float4 w0 = reinterpret_cast<const float4*>(gff)[lane];
    float4 w1 = reinterpret_cast<const float4*>(gff + 256)[lane];
    float4 w2 = reinterpret_cast<const float4*>(gff + 512)[lane];
    float dot = x0 * (w0.x + w2.x) + rv.x * (w1.x - w2.x)
              + x1 * (w0.y + w2.y) + rv.y * (w1.y - w2.y)
              + x2 * (w0.z + w2.z) + rv.z * (w1.z - w2.z)
              + x3 * (w0.w + w2.w) + rv.w * (w1.w - w2.w);
    dot = wave_sum(dot);
    float gate = 1.0f / (1.0f + __expf(-dot));
    float n0 = fmaf(x0 - rv.x, gate, rv.x);
    float n1 = fmaf(x1 - rv.y, gate, rv.y);
    float n2 = fmaf(x2 - rv.z, gate, rv.z);
    float n3 = fmaf(x3 - rv.w, gate, rv.w);
    if (LAST) {
      float4 wo4 = reinterpret_cast<const float4*>(Wout)[lane];
      float z = n0 * wo4.x + n1 * wo4.y + n2 * wo4.z + n3 * wo4.w;
      z = wave_sum(z);
      if (lane == 0) {
        z += bout[0];
        if (grow < HALF_N) {
          out[HALF_N + grow] = z;
        } else {
          int jj = grow - HALF_N;
          out[jj] = z;
          out[2 * HALF_N + jj] = z;
        }
      }
    } else {
      float4 o; o.x = n0; o.y = n1; o.z = n2; o.w = n3;
      reinterpret_cast<float4*>(nodes + (size_t)grow * 256)[lane] = o;
      if (grow < HALF_N) {
        float mu = wave_sum(n0 + n1 + n2 + n3) * (1.0f / DIM);
        float d0 = n0 - mu, d1 = n1 - mu, d2 = n2 - mu, d3 = n3 - mu;
        float var = wave_sum(d0*d0 + d1*d1 + d2*d2 + d3*d3) * (1.0f / DIM);
        float rs = rsqrtf(var + 1e-5f);
        float4 gv = reinterpret_cast<const float4*>(ln1g)[lane];
        float4 bv = reinterpret_cast<const float4*>(ln1b)[lane];
        bf16x4 ob;
        ob[0] = (bf16)(d0 * rs * gv.x + bv.x);
        ob[1] = (bf16)(d1 * rs * gv.y + bv.y);
        ob[2] = (bf16)(d2 * rs * gv.z + bv.z);
        ob[3] = (bf16)(d3 * rs * gv.w + bv.w);
        *reinterpret_cast<bf16x4*>(A2 + (size_t)grow * 512 + lane * 4) = ob;
      }
    }
  }
}

// ---------------- ELL build ----------------
__global__ void ell_build(const int* __restrict__ ei, int* __restrict__ deg,
                          int* __restrict__ ell) {
  int e = blockIdx.x * 256 + threadIdx.x;
  if (e >= N_EDGES) return;
  int s = ei[e], d = ei[N_EDGES + e];
  int pos = atomicAdd(&deg[d], 1);
  if (pos < MAXDEG) ell[d * MAXDEG + pos] = s;
}

// ---------------- attention gather (wave per dst, online softmax, bf16) ------
// qkv layout [HALF][1024]: q (0..255) | interleaved k/v (256..767) | eB (768..1023)
__global__ void attn_gather(const int* __restrict__ deg, const int* __restrict__ ell,
                            const bf16* __restrict__ qkv, bf16* __restrict__ agg) {
  int d = blockIdx.x * 4 + (threadIdx.x >> 6);
  if (d >= HALF_N) return;
  int lane = threadIdx.x & 63;
  int cnt = deg[d]; if (cnt > MAXDEG) cnt = MAXDEG;
  const bf16* qr = qkv + (size_t)d * 1024;
  bf16x4 qb = *reinterpret_cast<const bf16x4*>(qr + lane * 4);
  float q0 = (float)qb[0], q1 = (float)qb[1], q2 = (float)qb[2], q3 = (float)qb[3];
  float m = -INFINITY, den = 0.0f, a0 = 0.0f, a1 = 0.0f, a2 = 0.0f, a3 = 0.0f;
  for (int i = 0; i < cnt; ++i) {
    int s = ell[d * MAXDEG + i];
    bf16x8 kv8 = *reinterpret_cast<const bf16x8*>(qkv + (size_t)s * 1024 + 256 + lane * 8);
    float p = q0 * (float)kv8[0] + q1 * (float)kv8[1] +
              q2 * (float)kv8[2] + q3 * (float)kv8[3];
    p += __shfl_xor(p, 1); p += __shfl_xor(p, 2);
    p += __shfl_xor(p, 4); p += __shfl_xor(p, 8);
    float sim = p * 0.125f;
    float nm = fmaxf(m, sim);
    float sc = __expf(m - nm);
    float w  = __expf(sim - nm);
    den = den * sc + w;
    a0 = a0 * sc + w * (float)kv8[4];
    a1 = a1 * sc + w * (float)kv8[5];
    a2 = a2 * sc + w * (float)kv8[6];
    a3 = a3 * sc + w * (float)kv8[7];
    m = nm;
  }
  bf16x4 o;
  if (cnt > 0) {
    float inv = 1.0f / den;
    bf16x4 eb = *reinterpret_cast<const bf16x4*>(qr + 768 + lane * 4);
    o[0] = (bf16)(a0 * inv + (float)eb[0]);
    o[1] = (bf16)(a1 * inv + (float)eb[1]);
    o[2] = (bf16)(a2 * inv + (float)eb[2]);
    o[3] = (bf16)(a3 * inv + (float)eb[3]);
  } else {
    o[0] = (bf16)0.0f; o[1] = (bf16)0.0f; o[2] = (bf16)0.0f; o[3] = (bf16)0.0f;
  }
  *reinterpret_cast<bf16x4*>(agg + (size_t)d * DIM + lane * 4) = o;
}

// ---------------- gated-residual + LN (upper rows: x = fb broadcast) ---------
template<int DO_LN>
__global__ void gr_ln(const float* __restrict__ fb,
                      float* __restrict__ nodes, const float* __restrict__ w,
                      const float* __restrict__ g, const float* __restrict__ b,
                      bf16* __restrict__ xn, int rows) {
  int r = blockIdx.x * 4 + (threadIdx.x >> 6);
  if (r >= rows) return;
  int lane = threadIdx.x & 63;
  float4 f = reinterpret_cast<const float4*>(fb)[lane];
  float x0 = f.x, x1 = f.y, x2 = f.z, x3 = f.w;
  float4 rv = reinterpret_cast<const float4*>(nodes + (size_t)r * DIM)[lane];
  float4 w0 = reinterpret_cast<const float4*>(w)[lane];
  float4 w1 = reinterpret_cast<const float4*>(w + 256)[lane];
  float4 w2 = reinterpret_cast<const float4*>(w + 512)[lane];
  float p = x0 * (w0.x + w2.x) + rv.x * (w1.x - w2.x)
          + x1 * (w0.y + w2.y) + rv.y * (w1.y - w2.y)
          + x2 * (w0.z + w2.z) + rv.z * (w1.z - w2.z)
          + x3 * (w0.w + w2.w) + rv.w * (w1.w - w2.w);
  p = wave_sum(p);
  float gate = 1.0f / (1.0f + __expf(-p));
  float n0 = x0 * gate + rv.x * (1.0f - gate);
  float n1 = x1 * gate + rv.y * (1.0f - gate);
  float n2 = x2 * gate + rv.z * (1.0f - gate);
  float n3 = x3 * gate + rv.w * (1.0f - gate);
  float4 o; o.x = n0; o.y = n1; o.z = n2; o.w = n3;
  reinterpret_cast<float4*>(nodes + (size_t)r * DIM)[lane] = o;
  if (DO_LN) {
    float mu = wave_sum(n0 + n1 + n2 + n3) * (1.0f / DIM);
    float d0 = n0 - mu, d1 = n1 - mu, d2 = n2 - mu, d3 = n3 - mu;
    float var = wave_sum(d0*d0 + d1*d1 + d2*d2 + d3*d3) * (1.0f / DIM);
    float rs = rsqrtf(var + 1e-5f);
    float4 gv = reinterpret_cast<const float4*>(g)[lane];
    float4 bv = reinterpret_cast<const float4*>(b)[lane];
    bf16x4 ob;
    ob[0] = (bf16)(d0 * rs * gv.x + bv.x);
    ob[1] = (bf16)(d1 * rs * gv.y + bv.y);
    ob[2] = (bf16)(d2 * rs * gv.z + bv.z);
    ob[3] = (bf16)(d3 * rs * gv.w + bv.w);
    *reinterpret_cast<bf16x4*>(xn + (size_t)r * DIM + lane * 4) = ob;
  }
}

// ---------------- weight prep: chunk-packed bf16 layouts ----------------
__global__ void prep_w(const float* __restrict__ Wq, const float* __restrict__ Wkv,
                       const float* __restrict__ We, const float* __restrict__ Wo,
                       const float* __restrict__ W1, const float* __restrict__ W2,
                       bf16* __restrict__ wt) {
  int idx = blockIdx.x * 256 + threadIdx.x;
  if (idx >= 2 * WT_LAYER) return;
  int l = idx / WT_LAYER, r = idx % WT_LAYER;
  float v;
  if (r < 524288) {                       // qkve: 8 x [64 k8][128 n][8 e], k/v interleaved
    int jn = r >> 16, t = r & 65535;
    int k8 = t >> 10, u = t & 1023, n = u >> 3, e = u & 7;
    int ncol = jn * 128 + n, k = k8 * 8 + e;
    if (ncol < 256) {
      v = (k < 256) ? Wq[l * 65536 + k * 256 + ncol] : 0.0f;
    } else if (ncol < 768) {
      int u2 = ncol - 256;
      int c = (u2 >> 3) * 4 + (u2 & 3);
      int half = (u2 >> 2) & 1;
      if (k < 256) v = Wkv[l * 131072 + k * 512 + half * 256 + c];
      else         v = We[l * 131072 + (k - 256) * 256 + c];
    } else {
      int c = ncol - 768;
      v = (k < 256) ? 0.0f : We[l * 131072 + k * 256 + c];
    }
  } else if (r < 589824) {                // Wo: 2 x [32 k8][128 n][8 e]
    int rr = r - 524288;
    int jn = rr >> 15, t = rr & 32767;
    int k8 = t >> 10, u = t & 1023, n = u >> 3, e = u & 7;
    v = Wo[l * 65536 + (k8 * 8 + e) * 256 + jn * 128 + n];
  } else if (r < 851968) {                // W1: 8 x [32 k8][128 n][8 e]
    int rr = r - 589824;
    int j = rr >> 15, t = rr & 32767;
    int k8 = t >> 10, u = t & 1023, n = u >> 3, e = u & 7;
    v = W1[l * 262144 + (k8 * 8 + e) * 1024 + j * 128 + n];
  } else {                                // W2: 8 x [16 k8][256 n][8 e]
    int rr = r - 851968;
    int j = rr >> 15, t = rr & 32767;
    int k8 = t >> 11, u = t & 2047, n = u >> 3, e = u & 7;
    v = W2[l * 262144 + (j * 128 + k8 * 8 + e) * 256 + n];
  }
  wt[idx] = (bf16)v;
}

// qkve bias: [2][1024] = [bq | interleaved bk/bv | be]
__global__ void prep_bias(const float* __restrict__ bq, const float* __restrict__ bkv,
                          const float* __restrict__ be, float* __restrict__ biasq) {
  int i = blockIdx.x * 256 + threadIdx.x;
  if (i >= 2048) return;
  int l = i >> 10, n = i & 1023;
  float v;
  if (n < 256) v = bq[l * 256 + n];
  else if (n < 768) {
    int u2 = n - 256;
    int c = (u2 >> 3) * 4 + (u2 & 3);
    int half = (u2 >> 2) & 1;
    v = bkv[l * 512 + half * 256 + c];
  } else v = be[l * 256 + (n - 768)];
  biasq[i] = v;
}

// x (fp32) -> A2 right half (bf16, stride 512)
__global__ void prep_x(const float* __restrict__ x, bf16* __restrict__ A2) {
  int i = blockIdx.x * 256 + threadIdx.x;
  if (i >= HALF_N * 64) return;
  int row = i >> 6, c = i & 63;
  float4 v = reinterpret_cast<const float4*>(x)[i];
  bf16x4 o;
  o[0] = (bf16)v.x; o[1] = (bf16)v.y; o[2] = (bf16)v.z; o[3] = (bf16)v.w;
  *reinterpret_cast<bf16x4*>(A2 + (size_t)row * 512 + 256 + c * 4) = o;
}

extern "C" void kernel_launch(void* const* d_in, const int* in_sizes, int n_in,
                              void* d_out, int out_size, void* d_ws, size_t ws_size,
                              hipStream_t stream) {
  const float* x     = (const float*)d_in[0];
  const int*   ei    = (const int*)d_in[1];
  const float* ln1_g = (const float*)d_in[2];
  const float* ln1_b = (const float*)d_in[3];
  const float* Wq    = (const float*)d_in[4];
  const float* bq    = (const float*)d_in[5];
  const float* Wkv   = (const float*)d_in[6];
  const float* bkv   = (const float*)d_in[7];
  const float* We    = (const float*)d_in[8];
  const float* be    = (const float*)d_in[9];
  const float* Wo    = (const float*)d_in[10];
  const float* bo    = (const float*)d_in[11];
  const float* g_attn= (const float*)d_in[12];
  const float* ln2_g = (const float*)d_in[13];
  const float* ln2_b = (const float*)d_in[14];
  const float* W1    = (const float*)d_in[15];
  const float* b1    = (const float*)d_in[16];
  const float* W2    = (const float*)d_in[17];
  const float* b2    = (const float*)d_in[18];
  const float* g_ff  = (const float*)d_in[19];
  const float* Wout  = (const float*)d_in[20];
  const float* bout  = (const float*)d_in[21];
  float* out = (float*)d_out;

  char* base = (char*)d_ws;
  float* nodes   = (float*)base;  base += (size_t)N_NODES * DIM * 4;      // 51.2 MB
  bf16*  A2      = (bf16*)base;   base += (size_t)HALF_N * 512 * 2;       // 25.6 MB
  bf16*  xn_bf   = (bf16*)base;   base += (size_t)N_NODES * DIM * 2;      // 25.6 MB
  bf16*  qkv     = (bf16*)base;   base += (size_t)HALF_N * 1024 * 2;      // 51.2 MB
  bf16*  agg     = (bf16*)base;   base += (size_t)HALF_N * DIM * 2;       // 12.8 MB
  bf16*  wt      = (bf16*)base;   base += (size_t)2 * WT_LAYER * 2;       // 4.5 MB
  float* biasq   = (float*)base;  base += 2048 * 4;
  int*   deg     = (int*)base;    base += HALF_N * 4;
  int*   ell     = (int*)base;    base += (size_t)HALF_N * MAXDEG * 4;    // 6.4 MB

  // one-time prep
  hipMemcpyAsync(nodes, x, (size_t)N_NODES * DIM * sizeof(float),
                 hipMemcpyDeviceToDevice, stream);
  prep_w<<<(2 * WT_LAYER + 255) / 256, 256, 0, stream>>>(Wq, Wkv, We, Wo, W1, W2, wt);
  prep_bias<<<8, 256, 0, stream>>>(bq, bkv, be, biasq);
  prep_x<<<(HALF_N * 64 + 255) / 256, 256, 0, stream>>>(x, A2);
  hipMemsetAsync(deg, 0, HALF_N * sizeof(int), stream);
  ell_build<<<(N_EDGES + 255) / 256, 256, 0, stream>>>(ei, deg, ell);

  const int GP_H = (HALF_N + 63) / 64;    // 391
  const int GP_N = (N_NODES + 63) / 64;   // 782

  for (int l = 0; l < NDEPTH; ++l) {
    const bf16* wl = wt + (size_t)l * WT_LAYER;
    if (l == 0)
      ln0_kernel<<<(HALF_N + 3) / 4, 256, 0, stream>>>(x, ln1_g, ln1_b, A2);
    // qkv|eB = [xn|x] @ qkveT + bias (k/v interleaved cols)
    gemm_nloop<512, 8><<<GP_H, 256, 0, stream>>>(A2, wl + WT_QKVE, biasq + l * 1024, qkv, HALF_N);
    // attention gather (+eB)
    attn_gather<<<(HALF_N + 3) / 4, 256, 0, stream>>>(deg, ell, qkv, agg);
    // attn_out = agg @ Wo + bo, fused gr1 + LN2 (lower rows)
    wo_fused<<<GP_H, 256, 0, stream>>>(agg, wl + WT_WO, bo + l * DIM,
                                       g_attn + l * 768, ln2_g + l * DIM, ln2_b + l * DIM,
                                       nodes, xn_bf, HALF_N);
    // upper rows: x = bo broadcast, gr1 + LN2
    gr_ln<1><<<(HALF_N + 3) / 4, 256, 0, stream>>>(
        bo + l * DIM, nodes + (size_t)HALF_N * DIM, g_attn + l * 768,
        ln2_g + l * DIM, ln2_b + l * DIM, xn_bf + (size_t)HALF_N * DIM, HALF_N);
    // fused FF + gr2 (+LN1next into A2 | +out-proj)
    if (l < NDEPTH - 1) {
      ff_fused<0><<<GP_N, 512, 0, stream>>>(
          xn_bf, wl + WT_W1, b1 + l * 1024, wl + WT_W2, b2 + l * DIM,
          nodes, g_ff + l * 768, ln1_g + (l + 1) * DIM, ln1_b + (l + 1) * DIM, A2,
          nullptr, nullptr, nullptr, N_NODES);
    } else {
      ff_fused<1><<<GP_N, 512, 0, stream>>>(
          xn_bf, wl + WT_W1, b1 + l * 1024, wl + WT_W2, b2 + l * DIM,
          nodes, g_ff + l * 768, nullptr, nullptr, nullptr,
          Wout, bout, out, N_NODES);
    }
  }
}

// Round 7
// 509.671 us; speedup vs baseline: 2.5993x; 2.5993x over previous
//
#include <hip/hip_runtime.h>
#include <cmath>

#define N_NODES 50000
#define N_EDGES 100000
#define HALF_N  25000
#define DIM     256
#define NDEPTH  2
#define MAXDEG  64

// per-layer weight-buffer offsets (bf16 elements), chunk-packed layouts
#define WT_QKVE 0          // 8 tiles x [64 k8][128 n] bf16x8  (k/v interleaved cols)
#define WT_WO   524288     // 2 tiles x [32 k8][128 n]
#define WT_W1   589824     // 8 chunks x [32 k8][128 n]
#define WT_W2   851968     // 8 chunks x [16 k8][256 n]
#define WT_LAYER 1114112

typedef __bf16 bf16;
typedef bf16 bf16x8 __attribute__((ext_vector_type(8)));
typedef bf16 bf16x4 __attribute__((ext_vector_type(4)));
typedef float f32x4 __attribute__((ext_vector_type(4)));

__device__ __forceinline__ float wave_sum(float v) {
  v += __shfl_xor(v, 1);
  v += __shfl_xor(v, 2);
  v += __shfl_xor(v, 4);
  v += __shfl_xor(v, 8);
  v += __shfl_xor(v, 16);
  v += __shfl_xor(v, 32);
  return v;
}

// exact-GELU via A&S 7.1.26 erf (abs err ~1.5e-7)
__device__ __forceinline__ float fast_gelu(float v) {
  float ax = fabsf(v) * 0.70710678118654752f;
  float t = __builtin_amdgcn_rcpf(fmaf(0.3275911f, ax, 1.0f));
  float p = t * fmaf(t, fmaf(t, fmaf(t, fmaf(t, 1.061405429f, -1.453152027f),
                                     1.421413741f), -0.284496736f), 0.254829592f);
  float e = __expf(-ax * ax);
  float erfv = fmaf(-p, e, 1.0f);
  float ph = copysignf(erfv, v);
  return 0.5f * v * (1.0f + ph);
}

// ---------------- layer-0 LN1: x -> A2 left half (stride 512) ----------------
__global__ void ln0_kernel(const float* __restrict__ in, const float* __restrict__ g,
                           const float* __restrict__ b, bf16* __restrict__ A2) {
  int row = blockIdx.x * 4 + (threadIdx.x >> 6);
  if (row >= HALF_N) return;
  int lane = threadIdx.x & 63;
  float4 x = reinterpret_cast<const float4*>(in + (size_t)row * DIM)[lane];
  float mu = wave_sum(x.x + x.y + x.z + x.w) * (1.0f / DIM);
  float d0 = x.x - mu, d1 = x.y - mu, d2 = x.z - mu, d3 = x.w - mu;
  float var = wave_sum(d0*d0 + d1*d1 + d2*d2 + d3*d3) * (1.0f / DIM);
  float r = rsqrtf(var + 1e-5f);
  float4 gv = reinterpret_cast<const float4*>(g)[lane];
  float4 bv = reinterpret_cast<const float4*>(b)[lane];
  bf16x4 o;
  o[0] = (bf16)(d0 * r * gv.x + bv.x);
  o[1] = (bf16)(d1 * r * gv.y + bv.y);
  o[2] = (bf16)(d2 * r * gv.z + bv.z);
  o[3] = (bf16)(d3 * r * gv.w + bv.w);
  *reinterpret_cast<bf16x4*>(A2 + (size_t)row * 512 + lane * 4) = o;
}

// ---------------- N-loop MFMA GEMM (qkve): A in LDS, W frags global->reg -----
// A [M][KK] bf16; Wp chunk-packed [NJ][KK/8][128] bf16x8; C [M][NJ*128] bf16.
template<int KK, int NJ>
__global__ __launch_bounds__(256, 2) void gemm_nloop(
    const bf16* __restrict__ A, const bf16* __restrict__ Wp,
    const float* __restrict__ bias, bf16* __restrict__ C, int M) {
  constexpr int STEPS = KK / 64;
  __shared__ bf16x8 As[KK * 8];        // [KK/8 k8][64 row]  (KK=512 -> 64 KB)
  __shared__ bf16 Cs[64 * 128];        // 16 KB
  const int tid = threadIdx.x;
  const int lane = tid & 63, wv = tid >> 6;
  const int wr = wv >> 1, wc = wv & 1;
  const int lm = lane & 15, kb = (lane >> 4) & 3;
  const int row0 = blockIdx.x * 64;
#pragma unroll
  for (int i = 0; i < KK / 32; ++i) {
    int idx = tid + i * 256;
    int row = idx & 63, k8 = idx >> 6;
    int rga = row0 + row; if (rga >= M) rga = M - 1;
    As[idx] = *reinterpret_cast<const bf16x8*>(A + (size_t)rga * KK + k8 * 8);
  }
  __syncthreads();
  const bf16x8* wb = reinterpret_cast<const bf16x8*>(Wp) + kb * 128 + wc * 64 + lm;
  for (int jn = 0; jn < NJ; ++jn) {
    f32x4 acc[2][4] = {};
    for (int st = 0; st < STEPS; ++st) {
#pragma unroll
      for (int ks = 0; ks < 2; ++ks) {
        bf16x8 bfr[4], af[2];
#pragma unroll
        for (int ni = 0; ni < 4; ++ni)
          bfr[ni] = wb[(size_t)jn * (KK * 16) + st * 1024 + ks * 512 + ni * 16];
#pragma unroll
        for (int mi = 0; mi < 2; ++mi)
          af[mi] = As[(st * 8 + ks * 4 + kb) * 64 + wr * 32 + mi * 16 + lm];
#pragma unroll
        for (int mi = 0; mi < 2; ++mi)
#pragma unroll
          for (int ni = 0; ni < 4; ++ni)
            acc[mi][ni] = __builtin_amdgcn_mfma_f32_16x16x32_bf16(af[mi], bfr[ni], acc[mi][ni], 0, 0, 0);
      }
    }
    __syncthreads();                   // prev jn's stores done reading Cs
#pragma unroll
    for (int ni = 0; ni < 4; ++ni) {
      int c = wc * 64 + ni * 16 + lm;
      float bval = bias[jn * 128 + c];
#pragma unroll
      for (int mi = 0; mi < 2; ++mi)
#pragma unroll
        for (int e = 0; e < 4; ++e) {
          int r = wr * 32 + mi * 16 + kb * 4 + e;
          Cs[r * 128 + c] = (bf16)(acc[mi][ni][e] + bval);
        }
    }
    __syncthreads();
    bf16x8* C8 = reinterpret_cast<bf16x8*>(C);
    const bf16x8* Cs8 = (const bf16x8*)Cs;
#pragma unroll
    for (int i = 0; i < 4; ++i) {
      int idx = tid + i * 256;
      int row = idx >> 4, c8 = idx & 15;
      int grow = row0 + row;
      if (grow < M) C8[(size_t)grow * (NJ * 16) + jn * 16 + c8] = Cs8[row * 16 + c8];
    }
  }
}

// ---------------- Wo GEMM fused with gr1 + LN2 (lower rows) ------------------
__global__ __launch_bounds__(256, 2) void wo_fused(
    const bf16* __restrict__ A, const bf16* __restrict__ Wp,
    const float* __restrict__ bo, const float* __restrict__ gattn,
    const float* __restrict__ ln2g, const float* __restrict__ ln2b,
    float* __restrict__ nodes, bf16* __restrict__ xn, int M) {
  __shared__ bf16x8 As[2048];          // 32 KB [32 k8][64 row]
  __shared__ bf16 Cs[64 * 256];        // 32 KB, XOR-swizzled chunks
  const int tid = threadIdx.x;
  const int lane = tid & 63, wv = tid >> 6;
  const int wr = wv >> 1, wc = wv & 1;
  const int lm = lane & 15, kb = (lane >> 4) & 3;
  const int row0 = blockIdx.x * 64;
#pragma unroll
  for (int i = 0; i < 8; ++i) {
    int idx = tid + i * 256;
    int row = idx & 63, k8 = idx >> 6;
    int rga = row0 + row; if (rga >= M) rga = M - 1;
    As[idx] = *reinterpret_cast<const bf16x8*>(A + (size_t)rga * 256 + k8 * 8);
  }
  __syncthreads();
  const bf16x8* wb = reinterpret_cast<const bf16x8*>(Wp) + kb * 128 + wc * 64 + lm;
  for (int jn = 0; jn < 2; ++jn) {
    f32x4 acc[2][4] = {};
#pragma unroll
    for (int st = 0; st < 4; ++st) {
#pragma unroll
      for (int ks = 0; ks < 2; ++ks) {
        bf16x8 bfr[4], af[2];
#pragma unroll
        for (int ni = 0; ni < 4; ++ni)
          bfr[ni] = wb[jn * 4096 + st * 1024 + ks * 512 + ni * 16];
#pragma unroll
        for (int mi = 0; mi < 2; ++mi)
          af[mi] = As[(st * 8 + ks * 4 + kb) * 64 + wr * 32 + mi * 16 + lm];
#pragma unroll
        for (int mi = 0; mi < 2; ++mi)
#pragma unroll
          for (int ni = 0; ni < 4; ++ni)
            acc[mi][ni] = __builtin_amdgcn_mfma_f32_16x16x32_bf16(af[mi], bfr[ni], acc[mi][ni], 0, 0, 0);
      }
    }
#pragma unroll
    for (int ni = 0; ni < 4; ++ni) {
      int cfull = jn * 128 + wc * 64 + ni * 16 + lm;
      float bval = bo[cfull];
#pragma unroll
      for (int mi = 0; mi < 2; ++mi)
#pragma unroll
        for (int e = 0; e < 4; ++e) {
          int r = wr * 32 + mi * 16 + kb * 4 + e;
          int ch = (cfull >> 3) ^ (r & 7);
          Cs[r * 256 + ch * 8 + (cfull & 7)] = (bf16)(acc[mi][ni][e] + bval);
        }
    }
  }
  __syncthreads();
  // fused gr1 + LN2: wave per row (coalesced float4 on nodes)
  for (int pass = 0; pass < 16; ++pass) {
    int r = pass * 4 + wv;
    int grow = row0 + r;
    if (grow >= M) continue;
    int ch = (lane >> 1) ^ (r & 7);
    bf16x4 c4 = *reinterpret_cast<const bf16x4*>(Cs + r * 256 + ch * 8 + (lane & 1) * 4);
    float x0 = (float)c4[0], x1 = (float)c4[1], x2 = (float)c4[2], x3 = (float)c4[3];
    float4 rv = reinterpret_cast<const float4*>(nodes + (size_t)grow * 256)[lane];
    float4 w0 = reinterpret_cast<const float4*>(gattn)[lane];
    float4 w1 = reinterpret_cast<const float4*>(gattn + 256)[lane];
    float4 w2 = reinterpret_cast<const float4*>(gattn + 512)[lane];
    float dot = x0 * (w0.x + w2.x) + rv.x * (w1.x - w2.x)
              + x1 * (w0.y + w2.y) + rv.y * (w1.y - w2.y)
              + x2 * (w0.z + w2.z) + rv.z * (w1.z - w2.z)
              + x3 * (w0.w + w2.w) + rv.w * (w1.w - w2.w);
    dot = wave_sum(dot);
    float gate = 1.0f / (1.0f + __expf(-dot));
    float n0 = fmaf(x0 - rv.x, gate, rv.x);
    float n1 = fmaf(x1 - rv.y, gate, rv.y);
    float n2 = fmaf(x2 - rv.z, gate, rv.z);
    float n3 = fmaf(x3 - rv.w, gate, rv.w);
    float4 o; o.x = n0; o.y = n1; o.z = n2; o.w = n3;
    reinterpret_cast<float4*>(nodes + (size_t)grow * 256)[lane] = o;
    float mu = wave_sum(n0 + n1 + n2 + n3) * (1.0f / DIM);
    float d0 = n0 - mu, d1 = n1 - mu, d2 = n2 - mu, d3 = n3 - mu;
    float var = wave_sum(d0*d0 + d1*d1 + d2*d2 + d3*d3) * (1.0f / DIM);
    float rs = rsqrtf(var + 1e-5f);
    float4 gv = reinterpret_cast<const float4*>(ln2g)[lane];
    float4 bv = reinterpret_cast<const float4*>(ln2b)[lane];
    bf16x4 ob;
    ob[0] = (bf16)(d0 * rs * gv.x + bv.x);
    ob[1] = (bf16)(d1 * rs * gv.y + bv.y);
    ob[2] = (bf16)(d2 * rs * gv.z + bv.z);
    ob[3] = (bf16)(d3 * rs * gv.w + bv.w);
    *reinterpret_cast<bf16x4*>(xn + (size_t)grow * 256 + lane * 4) = ob;
  }
}

// ---------------- fused FF + gr2 (+LN1next | +out-proj), 64-row panel --------
// A in LDS (Xs, Cs aliases), W1/W2 frags global->reg. LDS 48 KB.
template<int LAST>
__global__ __launch_bounds__(512, 4) void ff_fused(
    const bf16* __restrict__ A, const bf16* __restrict__ W1p,
    const float* __restrict__ b1, const bf16* __restrict__ W2p,
    const float* __restrict__ b2, float* __restrict__ nodes,
    const float* __restrict__ gff, const float* __restrict__ ln1g,
    const float* __restrict__ ln1b, bf16* __restrict__ A2,
    const float* __restrict__ Wout, const float* __restrict__ bout,
    float* __restrict__ out, int M) {
  __shared__ char smem[49152];
  bf16x8* Xs = (bf16x8*)smem;           // 2048 entries, 32 KB
  bf16*   Cs = (bf16*)smem;             // aliases Xs (used after last Xs read)
  bf16x8* Hs = (bf16x8*)(smem + 32768); // 1024 entries, 16 KB
  const int tid = threadIdx.x;
  const int lane = tid & 63, wv = tid >> 6;
  const int wr = wv >> 2, wc = wv & 3;
  const int lm = lane & 15, kb = (lane >> 4) & 3;
  const int row0 = blockIdx.x * 64;
#pragma unroll
  for (int i = 0; i < 4; ++i) {
    int idx = tid + i * 512;
    int row = idx & 63, k8 = idx >> 6;
    int rga = row0 + row; if (rga >= M) rga = M - 1;
    Xs[idx] = *reinterpret_cast<const bf16x8*>(A + (size_t)rga * 256 + k8 * 8);
  }
  __syncthreads();
  const bf16x8* w1b = (const bf16x8*)W1p + kb * 128 + wc * 32 + lm;
  const bf16x8* w2b = (const bf16x8*)W2p + kb * 256 + wc * 64 + lm;
  f32x4 acc[2][4] = {};
  bf16* hsb = (bf16*)Hs;
  for (int j = 0; j < 8; ++j) {
    f32x4 acc1[2][2] = {};
#pragma unroll
    for (int half = 0; half < 2; ++half) {
#pragma unroll
      for (int ks = 0; ks < 4; ++ks) {
        bf16x8 bfr[2], af[2];
#pragma unroll
        for (int ni = 0; ni < 2; ++ni)
          bfr[ni] = w1b[j * 4096 + half * 2048 + ks * 512 + ni * 16];
#pragma unroll
        for (int mi = 0; mi < 2; ++mi)
          af[mi] = Xs[(half * 16 + ks * 4 + kb) * 64 + wr * 32 + mi * 16 + lm];
#pragma unroll
        for (int mi = 0; mi < 2; ++mi)
#pragma unroll
          for (int ni = 0; ni < 2; ++ni)
            acc1[mi][ni] = __builtin_amdgcn_mfma_f32_16x16x32_bf16(af[mi], bfr[ni], acc1[mi][ni], 0, 0, 0);
      }
    }
    __syncthreads();                  // prev j's FF2 done reading Hs
#pragma unroll
    for (int ni = 0; ni < 2; ++ni) {
      int c = wc * 32 + ni * 16 + lm;
      float bval = b1[j * 128 + c];
#pragma unroll
      for (int mi = 0; mi < 2; ++mi)
#pragma unroll
        for (int e = 0; e < 4; ++e) {
          int r = wr * 32 + mi * 16 + kb * 4 + e;
          float v = fast_gelu(acc1[mi][ni][e] + bval);
          hsb[((c >> 3) * 64 + r) * 8 + (c & 7)] = (bf16)v;
        }
    }
    __syncthreads();                  // Hs visible
#pragma unroll
    for (int h2 = 0; h2 < 2; ++h2) {
#pragma unroll
      for (int ks = 0; ks < 2; ++ks) {
        bf16x8 bfr[4], af[2];
#pragma unroll
        for (int ni = 0; ni < 4; ++ni)
          bfr[ni] = w2b[j * 4096 + h2 * 2048 + ks * 1024 + ni * 16];
#pragma unroll
        for (int mi = 0; mi < 2; ++mi)
          af[mi] = Hs[(h2 * 8 + ks * 4 + kb) * 64 + wr * 32 + mi * 16 + lm];
#pragma unroll
        for (int mi = 0; mi < 2; ++mi)
#pragma unroll
          for (int ni = 0; ni < 4; ++ni)
            acc[mi][ni] = __builtin_amdgcn_mfma_f32_16x16x32_bf16(af[mi], bfr[ni], acc[mi][ni], 0, 0, 0);
      }
    }
  }
  // Cs aliases Xs; all Xs reads ended before the j=7 barriers. Other waves may
  // still be in FF2 (Hs/W2 only) -> safe to write Cs now.
#pragma unroll
  for (int ni = 0; ni < 4; ++ni) {
    int c = wc * 64 + ni * 16 + lm;
    float bval = b2[c];
#pragma unroll
    for (int mi = 0; mi < 2; ++mi)
#pragma unroll
      for (int e = 0; e < 4; ++e) {
        int r = wr * 32 + mi * 16 + kb * 4 + e;
        int ch = (c >> 3) ^ (r & 7);
        Cs[r * 256 + ch * 8 + (c & 7)] = (bf16)(acc[mi][ni][e] + bval);
      }
  }
  __syncthreads();
  // fused epilogue: wave per row (coalesced)
  for (int pass = 0; pass < 8; ++pass) {
    int r = pass * 8 + wv;
    int grow = row0 + r;
    if (grow >= M) continue;
    int ch = (lane >> 1) ^ (r & 7);
    bf16x4 c4 = *reinterpret_cast<const bf16x4*>(Cs + r * 256 + ch * 8 + (lane & 1) * 4);
    float x0 = (float)c4[0], x1 = (float)c4[1], x2 = (float)c4[2], x3 = (float)c4[3];
    float4 rv = reinterpret_cast<const float4*>(nodes + (size_t)grow * 256)[lane];
    float4 w0 = reinterpret_cast<const float4*>(gff)[lane];
    float4 w1 = reinterpret_cast<const float4*>(gff + 256)[lane];
    float4 w2 = reinterpret_cast<const float4*>(gff + 512)[lane];
    float dot = x0 * (w0.x + w2.x) + rv.x * (w1.x - w2.x)
              + x1 * (w0.y + w2.y) + rv.y * (w1.y - w2.y)
              + x2 * (w0.z + w2.z) + rv.z * (w1.z - w2.z)
              + x3 * (w0.w + w2.w) + rv.w * (w1.w - w2.w);
    dot = wave_sum(dot);
    float gate = 1.0f / (1.0f + __expf(-dot));
    float n0 = fmaf(x0 - rv.x, gate, rv.x);
    float n1 = fmaf(x1 - rv.y, gate, rv.y);
    float n2 = fmaf(x2 - rv.z, gate, rv.z);
    float n3 = fmaf(x3 - rv.w, gate, rv.w);
    if (LAST) {
      float4 wo4 = reinterpret_cast<const float4*>(Wout)[lane];
      float z = n0 * wo4.x + n1 * wo4.y + n2 * wo4.z + n3 * wo4.w;
      z = wave_sum(z);
      if (lane == 0) {
        z += bout[0];
        if (grow < HALF_N) {
          out[HALF_N + grow] = z;
        } else {
          int jj = grow - HALF_N;
          out[jj] = z;
          out[2 * HALF_N + jj] = z;
        }
      }
    } else {
      float4 o; o.x = n0; o.y = n1; o.z = n2; o.w = n3;
      reinterpret_cast<float4*>(nodes + (size_t)grow * 256)[lane] = o;
      if (grow < HALF_N) {
        float mu = wave_sum(n0 + n1 + n2 + n3) * (1.0f / DIM);
        float d0 = n0 - mu, d1 = n1 - mu, d2 = n2 - mu, d3 = n3 - mu;
        float var = wave_sum(d0*d0 + d1*d1 + d2*d2 + d3*d3) * (1.0f / DIM);
        float rs = rsqrtf(var + 1e-5f);
        float4 gv = reinterpret_cast<const float4*>(ln1g)[lane];
        float4 bv = reinterpret_cast<const float4*>(ln1b)[lane];
        bf16x4 ob;
        ob[0] = (bf16)(d0 * rs * gv.x + bv.x);
        ob[1] = (bf16)(d1 * rs * gv.y + bv.y);
        ob[2] = (bf16)(d2 * rs * gv.z + bv.z);
        ob[3] = (bf16)(d3 * rs * gv.w + bv.w);
        *reinterpret_cast<bf16x4*>(A2 + (size_t)grow * 512 + lane * 4) = ob;
      }
    }
  }
}

// ---------------- ELL build ----------------
__global__ void ell_build(const int* __restrict__ ei, int* __restrict__ deg,
                          int* __restrict__ ell) {
  int e = blockIdx.x * 256 + threadIdx.x;
  if (e >= N_EDGES) return;
  int s = ei[e], d = ei[N_EDGES + e];
  int pos = atomicAdd(&deg[d], 1);
  if (pos < MAXDEG) ell[d * MAXDEG + pos] = s;
}

// ---------------- attention gather (wave per dst, online softmax, bf16) ------
// qkv layout [HALF][1024]: q (0..255) | interleaved k/v (256..767) | eB (768..1023)
__global__ void attn_gather(const int* __restrict__ deg, const int* __restrict__ ell,
                            const bf16* __restrict__ qkv, bf16* __restrict__ agg) {
  int d = blockIdx.x * 4 + (threadIdx.x >> 6);
  if (d >= HALF_N) return;
  int lane = threadIdx.x & 63;
  int cnt = deg[d]; if (cnt > MAXDEG) cnt = MAXDEG;
  const bf16* qr = qkv + (size_t)d * 1024;
  bf16x4 qb = *reinterpret_cast<const bf16x4*>(qr + lane * 4);
  float q0 = (float)qb[0], q1 = (float)qb[1], q2 = (float)qb[2], q3 = (float)qb[3];
  float m = -INFINITY, den = 0.0f, a0 = 0.0f, a1 = 0.0f, a2 = 0.0f, a3 = 0.0f;
  for (int i = 0; i < cnt; ++i) {
    int s = ell[d * MAXDEG + i];
    bf16x8 kv8 = *reinterpret_cast<const bf16x8*>(qkv + (size_t)s * 1024 + 256 + lane * 8);
    float p = q0 * (float)kv8[0] + q1 * (float)kv8[1] +
              q2 * (float)kv8[2] + q3 * (float)kv8[3];
    p += __shfl_xor(p, 1); p += __shfl_xor(p, 2);
    p += __shfl_xor(p, 4); p += __shfl_xor(p, 8);
    float sim = p * 0.125f;
    float nm = fmaxf(m, sim);
    float sc = __expf(m - nm);
    float w  = __expf(sim - nm);
    den = den * sc + w;
    a0 = a0 * sc + w * (float)kv8[4];
    a1 = a1 * sc + w * (float)kv8[5];
    a2 = a2 * sc + w * (float)kv8[6];
    a3 = a3 * sc + w * (float)kv8[7];
    m = nm;
  }
  bf16x4 o;
  if (cnt > 0) {
    float inv = 1.0f / den;
    bf16x4 eb = *reinterpret_cast<const bf16x4*>(qr + 768 + lane * 4);
    o[0] = (bf16)(a0 * inv + (float)eb[0]);
    o[1] = (bf16)(a1 * inv + (float)eb[1]);
    o[2] = (bf16)(a2 * inv + (float)eb[2]);
    o[3] = (bf16)(a3 * inv + (float)eb[3]);
  } else {
    o[0] = (bf16)0.0f; o[1] = (bf16)0.0f; o[2] = (bf16)0.0f; o[3] = (bf16)0.0f;
  }
  *reinterpret_cast<bf16x4*>(agg + (size_t)d * DIM + lane * 4) = o;
}

// ---------------- gated-residual + LN (upper rows: x = fb broadcast) ---------
template<int DO_LN>
__global__ void gr_ln(const float* __restrict__ fb,
                      float* __restrict__ nodes, const float* __restrict__ w,
                      const float* __restrict__ g, const float* __restrict__ b,
                      bf16* __restrict__ xn, int rows) {
  int r = blockIdx.x * 4 + (threadIdx.x >> 6);
  if (r >= rows) return;
  int lane = threadIdx.x & 63;
  float4 f = reinterpret_cast<const float4*>(fb)[lane];
  float x0 = f.x, x1 = f.y, x2 = f.z, x3 = f.w;
  float4 rv = reinterpret_cast<const float4*>(nodes + (size_t)r * DIM)[lane];
  float4 w0 = reinterpret_cast<const float4*>(w)[lane];
  float4 w1 = reinterpret_cast<const float4*>(w + 256)[lane];
  float4 w2 = reinterpret_cast<const float4*>(w + 512)[lane];
  float p = x0 * (w0.x + w2.x) + rv.x * (w1.x - w2.x)
          + x1 * (w0.y + w2.y) + rv.y * (w1.y - w2.y)
          + x2 * (w0.z + w2.z) + rv.z * (w1.z - w2.z)
          + x3 * (w0.w + w2.w) + rv.w * (w1.w - w2.w);
  p = wave_sum(p);
  float gate = 1.0f / (1.0f + __expf(-p));
  float n0 = x0 * gate + rv.x * (1.0f - gate);
  float n1 = x1 * gate + rv.y * (1.0f - gate);
  float n2 = x2 * gate + rv.z * (1.0f - gate);
  float n3 = x3 * gate + rv.w * (1.0f - gate);
  float4 o; o.x = n0; o.y = n1; o.z = n2; o.w = n3;
  reinterpret_cast<float4*>(nodes + (size_t)r * DIM)[lane] = o;
  if (DO_LN) {
    float mu = wave_sum(n0 + n1 + n2 + n3) * (1.0f / DIM);
    float d0 = n0 - mu, d1 = n1 - mu, d2 = n2 - mu, d3 = n3 - mu;
    float var = wave_sum(d0*d0 + d1*d1 + d2*d2 + d3*d3) * (1.0f / DIM);
    float rs = rsqrtf(var + 1e-5f);
    float4 gv = reinterpret_cast<const float4*>(g)[lane];
    float4 bv = reinterpret_cast<const float4*>(b)[lane];
    bf16x4 ob;
    ob[0] = (bf16)(d0 * rs * gv.x + bv.x);
    ob[1] = (bf16)(d1 * rs * gv.y + bv.y);
    ob[2] = (bf16)(d2 * rs * gv.z + bv.z);
    ob[3] = (bf16)(d3 * rs * gv.w + bv.w);
    *reinterpret_cast<bf16x4*>(xn + (size_t)r * DIM + lane * 4) = ob;
  }
}

// ---------------- weight prep: chunk-packed bf16 layouts ----------------
__global__ void prep_w(const float* __restrict__ Wq, const float* __restrict__ Wkv,
                       const float* __restrict__ We, const float* __restrict__ Wo,
                       const float* __restrict__ W1, const float* __restrict__ W2,
                       bf16* __restrict__ wt) {
  int idx = blockIdx.x * 256 + threadIdx.x;
  if (idx >= 2 * WT_LAYER) return;
  int l = idx / WT_LAYER, r = idx % WT_LAYER;
  float v;
  if (r < 524288) {                       // qkve: 8 x [64 k8][128 n][8 e], k/v interleaved
    int jn = r >> 16, t = r & 65535;
    int k8 = t >> 10, u = t & 1023, n = u >> 3, e = u & 7;
    int ncol = jn * 128 + n, k = k8 * 8 + e;
    if (ncol < 256) {
      v = (k < 256) ? Wq[l * 65536 + k * 256 + ncol] : 0.0f;
    } else if (ncol < 768) {
      int u2 = ncol - 256;
      int c = (u2 >> 3) * 4 + (u2 & 3);
      int half = (u2 >> 2) & 1;
      if (k < 256) v = Wkv[l * 131072 + k * 512 + half * 256 + c];
      else         v = We[l * 131072 + (k - 256) * 256 + c];
    } else {
      int c = ncol - 768;
      v = (k < 256) ? 0.0f : We[l * 131072 + k * 256 + c];
    }
  } else if (r < 589824) {                // Wo: 2 x [32 k8][128 n][8 e]
    int rr = r - 524288;
    int jn = rr >> 15, t = rr & 32767;
    int k8 = t >> 10, u = t & 1023, n = u >> 3, e = u & 7;
    v = Wo[l * 65536 + (k8 * 8 + e) * 256 + jn * 128 + n];
  } else if (r < 851968) {                // W1: 8 x [32 k8][128 n][8 e]
    int rr = r - 589824;
    int j = rr >> 15, t = rr & 32767;
    int k8 = t >> 10, u = t & 1023, n = u >> 3, e = u & 7;
    v = W1[l * 262144 + (k8 * 8 + e) * 1024 + j * 128 + n];
  } else {                                // W2: 8 x [16 k8][256 n][8 e]
    int rr = r - 851968;
    int j = rr >> 15, t = rr & 32767;
    int k8 = t >> 11, u = t & 2047, n = u >> 3, e = u & 7;
    v = W2[l * 262144 + (j * 128 + k8 * 8 + e) * 256 + n];
  }
  wt[idx] = (bf16)v;
}

// qkve bias: [2][1024] = [bq | interleaved bk/bv | be]
__global__ void prep_bias(const float* __restrict__ bq, const float* __restrict__ bkv,
                          const float* __restrict__ be, float* __restrict__ biasq) {
  int i = blockIdx.x * 256 + threadIdx.x;
  if (i >= 2048) return;
  int l = i >> 10, n = i & 1023;
  float v;
  if (n < 256) v = bq[l * 256 + n];
  else if (n < 768) {
    int u2 = n - 256;
    int c = (u2 >> 3) * 4 + (u2 & 3);
    int half = (u2 >> 2) & 1;
    v = bkv[l * 512 + half * 256 + c];
  } else v = be[l * 256 + (n - 768)];
  biasq[i] = v;
}

// x (fp32) -> A2 right half (bf16, stride 512)
__global__ void prep_x(const float* __restrict__ x, bf16* __restrict__ A2) {
  int i = blockIdx.x * 256 + threadIdx.x;
  if (i >= HALF_N * 64) return;
  int row = i >> 6, c = i & 63;
  float4 v = reinterpret_cast<const float4*>(x)[i];
  bf16x4 o;
  o[0] = (bf16)v.x; o[1] = (bf16)v.y; o[2] = (bf16)v.z; o[3] = (bf16)v.w;
  *reinterpret_cast<bf16x4*>(A2 + (size_t)row * 512 + 256 + c * 4) = o;
}

extern "C" void kernel_launch(void* const* d_in, const int* in_sizes, int n_in,
                              void* d_out, int out_size, void* d_ws, size_t ws_size,
                              hipStream_t stream) {
  const float* x     = (const float*)d_in[0];
  const int*   ei    = (const int*)d_in[1];
  const float* ln1_g = (const float*)d_in[2];
  const float* ln1_b = (const float*)d_in[3];
  const float* Wq    = (const float*)d_in[4];
  const float* bq    = (const float*)d_in[5];
  const float* Wkv   = (const float*)d_in[6];
  const float* bkv   = (const float*)d_in[7];
  const float* We    = (const float*)d_in[8];
  const float* be    = (const float*)d_in[9];
  const float* Wo    = (const float*)d_in[10];
  const float* bo    = (const float*)d_in[11];
  const float* g_attn= (const float*)d_in[12];
  const float* ln2_g = (const float*)d_in[13];
  const float* ln2_b = (const float*)d_in[14];
  const float* W1    = (const float*)d_in[15];
  const float* b1    = (const float*)d_in[16];
  const float* W2    = (const float*)d_in[17];
  const float* b2    = (const float*)d_in[18];
  const float* g_ff  = (const float*)d_in[19];
  const float* Wout  = (const float*)d_in[20];
  const float* bout  = (const float*)d_in[21];
  float* out = (float*)d_out;

  char* base = (char*)d_ws;
  float* nodes   = (float*)base;  base += (size_t)N_NODES * DIM * 4;      // 51.2 MB
  bf16*  A2      = (bf16*)base;   base += (size_t)HALF_N * 512 * 2;       // 25.6 MB
  bf16*  xn_bf   = (bf16*)base;   base += (size_t)N_NODES * DIM * 2;      // 25.6 MB
  bf16*  qkv     = (bf16*)base;   base += (size_t)HALF_N * 1024 * 2;      // 51.2 MB
  bf16*  agg     = (bf16*)base;   base += (size_t)HALF_N * DIM * 2;       // 12.8 MB
  bf16*  wt      = (bf16*)base;   base += (size_t)2 * WT_LAYER * 2;       // 4.5 MB
  float* biasq   = (float*)base;  base += 2048 * 4;
  int*   deg     = (int*)base;    base += HALF_N * 4;
  int*   ell     = (int*)base;    base += (size_t)HALF_N * MAXDEG * 4;    // 6.4 MB

  // one-time prep
  hipMemcpyAsync(nodes, x, (size_t)N_NODES * DIM * sizeof(float),
                 hipMemcpyDeviceToDevice, stream);
  prep_w<<<(2 * WT_LAYER + 255) / 256, 256, 0, stream>>>(Wq, Wkv, We, Wo, W1, W2, wt);
  prep_bias<<<8, 256, 0, stream>>>(bq, bkv, be, biasq);
  prep_x<<<(HALF_N * 64 + 255) / 256, 256, 0, stream>>>(x, A2);
  hipMemsetAsync(deg, 0, HALF_N * sizeof(int), stream);
  ell_build<<<(N_EDGES + 255) / 256, 256, 0, stream>>>(ei, deg, ell);

  const int GP_H = (HALF_N + 63) / 64;    // 391
  const int GP_N = (N_NODES + 63) / 64;   // 782

  for (int l = 0; l < NDEPTH; ++l) {
    const bf16* wl = wt + (size_t)l * WT_LAYER;
    if (l == 0)
      ln0_kernel<<<(HALF_N + 3) / 4, 256, 0, stream>>>(x, ln1_g, ln1_b, A2);
    // qkv|eB = [xn|x] @ qkveT + bias (k/v interleaved cols)
    gemm_nloop<512, 8><<<GP_H, 256, 0, stream>>>(A2, wl + WT_QKVE, biasq + l * 1024, qkv, HALF_N);
    // attention gather (+eB)
    attn_gather<<<(HALF_N + 3) / 4, 256, 0, stream>>>(deg, ell, qkv, agg);
    // attn_out = agg @ Wo + bo, fused gr1 + LN2 (lower rows)
    wo_fused<<<GP_H, 256, 0, stream>>>(agg, wl + WT_WO, bo + l * DIM,
                                       g_attn + l * 768, ln2_g + l * DIM, ln2_b + l * DIM,
                                       nodes, xn_bf, HALF_N);
    // upper rows: x = bo broadcast, gr1 + LN2
    gr_ln<1><<<(HALF_N + 3) / 4, 256, 0, stream>>>(
        bo + l * DIM, nodes + (size_t)HALF_N * DIM, g_attn + l * 768,
        ln2_g + l * DIM, ln2_b + l * DIM, xn_bf + (size_t)HALF_N * DIM, HALF_N);
    // fused FF + gr2 (+LN1next into A2 | +out-proj)
    if (l < NDEPTH - 1) {
      ff_fused<0><<<GP_N, 512, 0, stream>>>(
          xn_bf, wl + WT_W1, b1 + l * 1024, wl + WT_W2, b2 + l * DIM,
          nodes, g_ff + l * 768, ln1_g + (l + 1) * DIM, ln1_b + (l + 1) * DIM, A2,
          nullptr, nullptr, nullptr, N_NODES);
    } else {
      ff_fused<1><<<GP_N, 512, 0, stream>>>(
          xn_bf, wl + WT_W1, b1 + l * 1024, wl + WT_W2, b2 + l * DIM,
          nodes, g_ff + l * 768, nullptr, nullptr, nullptr,
          Wout, bout, out, N_NODES);
    }
  }
}

// Round 8
// 508.526 us; speedup vs baseline: 2.6051x; 1.0023x over previous
//
#include <hip/hip_runtime.h>
#include <cmath>

#define N_NODES 50000
#define N_EDGES 100000
#define HALF_N  25000
#define DIM     256
#define NDEPTH  2
#define MAXDEG  64

// per-layer weight-buffer offsets (bf16 elements), chunk-packed layouts
#define WT_QKVE 0          // 8 tiles x [64 k8][128 n] bf16x8  (k/v interleaved cols)
#define WT_WO   524288     // 2 tiles x [32 k8][128 n]
#define WT_W1   589824     // 8 chunks x [32 k8][128 n]
#define WT_W2   851968     // 8 chunks x [16 k8][256 n]
#define WT_LAYER 1114112

typedef __bf16 bf16;
typedef bf16 bf16x8 __attribute__((ext_vector_type(8)));
typedef bf16 bf16x4 __attribute__((ext_vector_type(4)));
typedef float f32x4 __attribute__((ext_vector_type(4)));

// LDS-only barrier: does NOT drain vmcnt, so global loads stay in flight.
// (__syncthreads emits s_waitcnt vmcnt(0) lgkmcnt(0) which serializes the
//  W-fragment pipeline across phases — the m97 barrier-drain tax.)
__device__ __forceinline__ void lds_barrier() {
  asm volatile("s_waitcnt lgkmcnt(0)" ::: "memory");
  __builtin_amdgcn_s_barrier();
  __builtin_amdgcn_sched_barrier(0);
}

__device__ __forceinline__ float wave_sum(float v) {
  v += __shfl_xor(v, 1);
  v += __shfl_xor(v, 2);
  v += __shfl_xor(v, 4);
  v += __shfl_xor(v, 8);
  v += __shfl_xor(v, 16);
  v += __shfl_xor(v, 32);
  return v;
}

// exact-GELU via A&S 7.1.26 erf (abs err ~1.5e-7)
__device__ __forceinline__ float fast_gelu(float v) {
  float ax = fabsf(v) * 0.70710678118654752f;
  float t = __builtin_amdgcn_rcpf(fmaf(0.3275911f, ax, 1.0f));
  float p = t * fmaf(t, fmaf(t, fmaf(t, fmaf(t, 1.061405429f, -1.453152027f),
                                     1.421413741f), -0.284496736f), 0.254829592f);
  float e = __expf(-ax * ax);
  float erfv = fmaf(-p, e, 1.0f);
  float ph = copysignf(erfv, v);
  return 0.5f * v * (1.0f + ph);
}

// ---------------- layer-0 LN1: x -> A2 left half (stride 512) ----------------
__global__ void ln0_kernel(const float* __restrict__ in, const float* __restrict__ g,
                           const float* __restrict__ b, bf16* __restrict__ A2) {
  int row = blockIdx.x * 4 + (threadIdx.x >> 6);
  if (row >= HALF_N) return;
  int lane = threadIdx.x & 63;
  float4 x = reinterpret_cast<const float4*>(in + (size_t)row * DIM)[lane];
  float mu = wave_sum(x.x + x.y + x.z + x.w) * (1.0f / DIM);
  float d0 = x.x - mu, d1 = x.y - mu, d2 = x.z - mu, d3 = x.w - mu;
  float var = wave_sum(d0*d0 + d1*d1 + d2*d2 + d3*d3) * (1.0f / DIM);
  float r = rsqrtf(var + 1e-5f);
  float4 gv = reinterpret_cast<const float4*>(g)[lane];
  float4 bv = reinterpret_cast<const float4*>(b)[lane];
  bf16x4 o;
  o[0] = (bf16)(d0 * r * gv.x + bv.x);
  o[1] = (bf16)(d1 * r * gv.y + bv.y);
  o[2] = (bf16)(d2 * r * gv.z + bv.z);
  o[3] = (bf16)(d3 * r * gv.w + bv.w);
  *reinterpret_cast<bf16x4*>(A2 + (size_t)row * 512 + lane * 4) = o;
}

// ---------------- N-loop MFMA GEMM (qkve): A in LDS, W frags global->reg -----
// A [M][KK] bf16; Wp chunk-packed [NJ][KK/8][128] bf16x8; C [M][NJ*128] bf16.
template<int KK, int NJ>
__global__ __launch_bounds__(256, 2) void gemm_nloop(
    const bf16* __restrict__ A, const bf16* __restrict__ Wp,
    const float* __restrict__ bias, bf16* __restrict__ C, int M) {
  constexpr int STEPS = KK / 64;
  __shared__ bf16x8 As[KK * 8];        // [KK/8 k8][64 row]  (KK=512 -> 64 KB)
  __shared__ bf16 Cs[64 * 128];        // 16 KB
  const int tid = threadIdx.x;
  const int lane = tid & 63, wv = tid >> 6;
  const int wr = wv >> 1, wc = wv & 1;
  const int lm = lane & 15, kb = (lane >> 4) & 3;
  const int row0 = blockIdx.x * 64;
#pragma unroll
  for (int i = 0; i < KK / 32; ++i) {
    int idx = tid + i * 256;
    int row = idx & 63, k8 = idx >> 6;
    int rga = row0 + row; if (rga >= M) rga = M - 1;
    As[idx] = *reinterpret_cast<const bf16x8*>(A + (size_t)rga * KK + k8 * 8);
  }
  lds_barrier();
  const bf16x8* wb = reinterpret_cast<const bf16x8*>(Wp) + kb * 128 + wc * 64 + lm;
  for (int jn = 0; jn < NJ; ++jn) {
    f32x4 acc[2][4] = {};
    for (int st = 0; st < STEPS; ++st) {
#pragma unroll
      for (int ks = 0; ks < 2; ++ks) {
        bf16x8 bfr[4], af[2];
#pragma unroll
        for (int ni = 0; ni < 4; ++ni)
          bfr[ni] = wb[(size_t)jn * (KK * 16) + st * 1024 + ks * 512 + ni * 16];
#pragma unroll
        for (int mi = 0; mi < 2; ++mi)
          af[mi] = As[(st * 8 + ks * 4 + kb) * 64 + wr * 32 + mi * 16 + lm];
#pragma unroll
        for (int mi = 0; mi < 2; ++mi)
#pragma unroll
          for (int ni = 0; ni < 4; ++ni)
            acc[mi][ni] = __builtin_amdgcn_mfma_f32_16x16x32_bf16(af[mi], bfr[ni], acc[mi][ni], 0, 0, 0);
      }
    }
    lds_barrier();                     // prev jn's Cs reads done
#pragma unroll
    for (int ni = 0; ni < 4; ++ni) {
      int c = wc * 64 + ni * 16 + lm;
      float bval = bias[jn * 128 + c];
#pragma unroll
      for (int mi = 0; mi < 2; ++mi)
#pragma unroll
        for (int e = 0; e < 4; ++e) {
          int r = wr * 32 + mi * 16 + kb * 4 + e;
          Cs[r * 128 + c] = (bf16)(acc[mi][ni][e] + bval);
        }
    }
    lds_barrier();
    bf16x8* C8 = reinterpret_cast<bf16x8*>(C);
    const bf16x8* Cs8 = (const bf16x8*)Cs;
#pragma unroll
    for (int i = 0; i < 4; ++i) {
      int idx = tid + i * 256;
      int row = idx >> 4, c8 = idx & 15;
      int grow = row0 + row;
      if (grow < M) C8[(size_t)grow * (NJ * 16) + jn * 16 + c8] = Cs8[row * 16 + c8];
    }
  }
}

// ---------------- Wo GEMM fused with gr1 + LN2 (lower rows) ------------------
__global__ __launch_bounds__(256, 2) void wo_fused(
    const bf16* __restrict__ A, const bf16* __restrict__ Wp,
    const float* __restrict__ bo, const float* __restrict__ gattn,
    const float* __restrict__ ln2g, const float* __restrict__ ln2b,
    float* __restrict__ nodes, bf16* __restrict__ xn, int M) {
  __shared__ bf16x8 As[2048];          // 32 KB [32 k8][64 row]
  __shared__ bf16 Cs[64 * 256];        // 32 KB, XOR-swizzled chunks
  const int tid = threadIdx.x;
  const int lane = tid & 63, wv = tid >> 6;
  const int wr = wv >> 1, wc = wv & 1;
  const int lm = lane & 15, kb = (lane >> 4) & 3;
  const int row0 = blockIdx.x * 64;
#pragma unroll
  for (int i = 0; i < 8; ++i) {
    int idx = tid + i * 256;
    int row = idx & 63, k8 = idx >> 6;
    int rga = row0 + row; if (rga >= M) rga = M - 1;
    As[idx] = *reinterpret_cast<const bf16x8*>(A + (size_t)rga * 256 + k8 * 8);
  }
  lds_barrier();
  const bf16x8* wb = reinterpret_cast<const bf16x8*>(Wp) + kb * 128 + wc * 64 + lm;
  for (int jn = 0; jn < 2; ++jn) {
    f32x4 acc[2][4] = {};
#pragma unroll
    for (int st = 0; st < 4; ++st) {
#pragma unroll
      for (int ks = 0; ks < 2; ++ks) {
        bf16x8 bfr[4], af[2];
#pragma unroll
        for (int ni = 0; ni < 4; ++ni)
          bfr[ni] = wb[jn * 4096 + st * 1024 + ks * 512 + ni * 16];
#pragma unroll
        for (int mi = 0; mi < 2; ++mi)
          af[mi] = As[(st * 8 + ks * 4 + kb) * 64 + wr * 32 + mi * 16 + lm];
#pragma unroll
        for (int mi = 0; mi < 2; ++mi)
#pragma unroll
          for (int ni = 0; ni < 4; ++ni)
            acc[mi][ni] = __builtin_amdgcn_mfma_f32_16x16x32_bf16(af[mi], bfr[ni], acc[mi][ni], 0, 0, 0);
      }
    }
#pragma unroll
    for (int ni = 0; ni < 4; ++ni) {
      int cfull = jn * 128 + wc * 64 + ni * 16 + lm;
      float bval = bo[cfull];
#pragma unroll
      for (int mi = 0; mi < 2; ++mi)
#pragma unroll
        for (int e = 0; e < 4; ++e) {
          int r = wr * 32 + mi * 16 + kb * 4 + e;
          int ch = (cfull >> 3) ^ (r & 7);
          Cs[r * 256 + ch * 8 + (cfull & 7)] = (bf16)(acc[mi][ni][e] + bval);
        }
    }
  }
  lds_barrier();
  // fused gr1 + LN2: wave per row (coalesced float4 on nodes)
  for (int pass = 0; pass < 16; ++pass) {
    int r = pass * 4 + wv;
    int grow = row0 + r;
    if (grow >= M) continue;
    int ch = (lane >> 1) ^ (r & 7);
    bf16x4 c4 = *reinterpret_cast<const bf16x4*>(Cs + r * 256 + ch * 8 + (lane & 1) * 4);
    float x0 = (float)c4[0], x1 = (float)c4[1], x2 = (float)c4[2], x3 = (float)c4[3];
    float4 rv = reinterpret_cast<const float4*>(nodes + (size_t)grow * 256)[lane];
    float4 w0 = reinterpret_cast<const float4*>(gattn)[lane];
    float4 w1 = reinterpret_cast<const float4*>(gattn + 256)[lane];
    float4 w2 = reinterpret_cast<const float4*>(gattn + 512)[lane];
    float dot = x0 * (w0.x + w2.x) + rv.x * (w1.x - w2.x)
              + x1 * (w0.y + w2.y) + rv.y * (w1.y - w2.y)
              + x2 * (w0.z + w2.z) + rv.z * (w1.z - w2.z)
              + x3 * (w0.w + w2.w) + rv.w * (w1.w - w2.w);
    dot = wave_sum(dot);
    float gate = 1.0f / (1.0f + __expf(-dot));
    float n0 = fmaf(x0 - rv.x, gate, rv.x);
    float n1 = fmaf(x1 - rv.y, gate, rv.y);
    float n2 = fmaf(x2 - rv.z, gate, rv.z);
    float n3 = fmaf(x3 - rv.w, gate, rv.w);
    float4 o; o.x = n0; o.y = n1; o.z = n2; o.w = n3;
    reinterpret_cast<float4*>(nodes + (size_t)grow * 256)[lane] = o;
    float mu = wave_sum(n0 + n1 + n2 + n3) * (1.0f / DIM);
    float d0 = n0 - mu, d1 = n1 - mu, d2 = n2 - mu, d3 = n3 - mu;
    float var = wave_sum(d0*d0 + d1*d1 + d2*d2 + d3*d3) * (1.0f / DIM);
    float rs = rsqrtf(var + 1e-5f);
    float4 gv = reinterpret_cast<const float4*>(ln2g)[lane];
    float4 bv = reinterpret_cast<const float4*>(ln2b)[lane];
    bf16x4 ob;
    ob[0] = (bf16)(d0 * rs * gv.x + bv.x);
    ob[1] = (bf16)(d1 * rs * gv.y + bv.y);
    ob[2] = (bf16)(d2 * rs * gv.z + bv.z);
    ob[3] = (bf16)(d3 * rs * gv.w + bv.w);
    *reinterpret_cast<bf16x4*>(xn + (size_t)grow * 256 + lane * 4) = ob;
  }
}

// ---------------- fused FF + gr2 (+LN1next | +out-proj), 64-row panel --------
// A in LDS (Xs, Cs aliases), W1/W2 frags global->reg with W2 prefetch.
template<int LAST>
__global__ __launch_bounds__(512, 4) void ff_fused(
    const bf16* __restrict__ A, const bf16* __restrict__ W1p,
    const float* __restrict__ b1, const bf16* __restrict__ W2p,
    const float* __restrict__ b2, float* __restrict__ nodes,
    const float* __restrict__ gff, const float* __restrict__ ln1g,
    const float* __restrict__ ln1b, bf16* __restrict__ A2,
    const float* __restrict__ Wout, const float* __restrict__ bout,
    float* __restrict__ out, int M) {
  __shared__ char smem[49152];
  bf16x8* Xs = (bf16x8*)smem;           // 2048 entries, 32 KB
  bf16*   Cs = (bf16*)smem;             // aliases Xs (used after last Xs read)
  bf16x8* Hs = (bf16x8*)(smem + 32768); // 1024 entries, 16 KB
  const int tid = threadIdx.x;
  const int lane = tid & 63, wv = tid >> 6;
  const int wr = wv >> 2, wc = wv & 3;
  const int lm = lane & 15, kb = (lane >> 4) & 3;
  const int row0 = blockIdx.x * 64;
#pragma unroll
  for (int i = 0; i < 4; ++i) {
    int idx = tid + i * 512;
    int row = idx & 63, k8 = idx >> 6;
    int rga = row0 + row; if (rga >= M) rga = M - 1;
    Xs[idx] = *reinterpret_cast<const bf16x8*>(A + (size_t)rga * 256 + k8 * 8);
  }
  lds_barrier();
  const bf16x8* w1b = (const bf16x8*)W1p + kb * 128 + wc * 32 + lm;
  const bf16x8* w2b = (const bf16x8*)W2p + kb * 256 + wc * 64 + lm;
  f32x4 acc[2][4] = {};
  bf16* hsb = (bf16*)Hs;
  for (int j = 0; j < 8; ++j) {
    // prefetch FF2 h2=0 W2 fragments; they ride across both barriers (no vmcnt drain)
    bf16x8 pf2[8];
#pragma unroll
    for (int ks = 0; ks < 2; ++ks)
#pragma unroll
      for (int ni = 0; ni < 4; ++ni)
        pf2[ks * 4 + ni] = w2b[j * 4096 + ks * 1024 + ni * 16];
    f32x4 acc1[2][2] = {};
#pragma unroll
    for (int half = 0; half < 2; ++half) {
#pragma unroll
      for (int ks = 0; ks < 4; ++ks) {
        bf16x8 bfr[2], af[2];
#pragma unroll
        for (int ni = 0; ni < 2; ++ni)
          bfr[ni] = w1b[j * 4096 + half * 2048 + ks * 512 + ni * 16];
#pragma unroll
        for (int mi = 0; mi < 2; ++mi)
          af[mi] = Xs[(half * 16 + ks * 4 + kb) * 64 + wr * 32 + mi * 16 + lm];
#pragma unroll
        for (int mi = 0; mi < 2; ++mi)
#pragma unroll
          for (int ni = 0; ni < 2; ++ni)
            acc1[mi][ni] = __builtin_amdgcn_mfma_f32_16x16x32_bf16(af[mi], bfr[ni], acc1[mi][ni], 0, 0, 0);
      }
    }
    lds_barrier();                    // prev j's FF2 done reading Hs
#pragma unroll
    for (int ni = 0; ni < 2; ++ni) {
      int c = wc * 32 + ni * 16 + lm;
      float bval = b1[j * 128 + c];
#pragma unroll
      for (int mi = 0; mi < 2; ++mi)
#pragma unroll
        for (int e = 0; e < 4; ++e) {
          int r = wr * 32 + mi * 16 + kb * 4 + e;
          float v = fast_gelu(acc1[mi][ni][e] + bval);
          hsb[((c >> 3) * 64 + r) * 8 + (c & 7)] = (bf16)v;
        }
    }
    lds_barrier();                    // Hs visible
#pragma unroll
    for (int h2 = 0; h2 < 2; ++h2) {
#pragma unroll
      for (int ks = 0; ks < 2; ++ks) {
        bf16x8 bfr[4], af[2];
#pragma unroll
        for (int ni = 0; ni < 4; ++ni)
          bfr[ni] = (h2 == 0) ? pf2[ks * 4 + ni]
                              : w2b[j * 4096 + 2048 + ks * 1024 + ni * 16];
#pragma unroll
        for (int mi = 0; mi < 2; ++mi)
          af[mi] = Hs[(h2 * 8 + ks * 4 + kb) * 64 + wr * 32 + mi * 16 + lm];
#pragma unroll
        for (int mi = 0; mi < 2; ++mi)
#pragma unroll
          for (int ni = 0; ni < 4; ++ni)
            acc[mi][ni] = __builtin_amdgcn_mfma_f32_16x16x32_bf16(af[mi], bfr[ni], acc[mi][ni], 0, 0, 0);
      }
    }
  }
  // Cs aliases Xs; collective barriers inside the j-loop guarantee all waves
  // finished FF1(j=7)'s Xs reads before any wave reaches here.
#pragma unroll
  for (int ni = 0; ni < 4; ++ni) {
    int c = wc * 64 + ni * 16 + lm;
    float bval = b2[c];
#pragma unroll
    for (int mi = 0; mi < 2; ++mi)
#pragma unroll
      for (int e = 0; e < 4; ++e) {
        int r = wr * 32 + mi * 16 + kb * 4 + e;
        int ch = (c >> 3) ^ (r & 7);
        Cs[r * 256 + ch * 8 + (c & 7)] = (bf16)(acc[mi][ni][e] + bval);
      }
  }
  lds_barrier();
  // fused epilogue: wave per row (coalesced)
  for (int pass = 0; pass < 8; ++pass) {
    int r = pass * 8 + wv;
    int grow = row0 + r;
    if (grow >= M) continue;
    int ch = (lane >> 1) ^ (r & 7);
    bf16x4 c4 = *reinterpret_cast<const bf16x4*>(Cs + r * 256 + ch * 8 + (lane & 1) * 4);
    float x0 = (float)c4[0], x1 = (float)c4[1], x2 = (float)c4[2], x3 = (float)c4[3];
    float4 rv = reinterpret_cast<const float4*>(nodes + (size_t)grow * 256)[lane];
    float4 w0 = reinterpret_cast<const float4*>(gff)[lane];
    float4 w1 = reinterpret_cast<const float4*>(gff + 256)[lane];
    float4 w2 = reinterpret_cast<const float4*>(gff + 512)[lane];
    float dot = x0 * (w0.x + w2.x) + rv.x * (w1.x - w2.x)
              + x1 * (w0.y + w2.y) + rv.y * (w1.y - w2.y)
              + x2 * (w0.z + w2.z) + rv.z * (w1.z - w2.z)
              + x3 * (w0.w + w2.w) + rv.w * (w1.w - w2.w);
    dot = wave_sum(dot);
    float gate = 1.0f / (1.0f + __expf(-dot));
    float n0 = fmaf(x0 - rv.x, gate, rv.x);
    float n1 = fmaf(x1 - rv.y, gate, rv.y);
    float n2 = fmaf(x2 - rv.z, gate, rv.z);
    float n3 = fmaf(x3 - rv.w, gate, rv.w);
    if (LAST) {
      float4 wo4 = reinterpret_cast<const float4*>(Wout)[lane];
      float z = n0 * wo4.x + n1 * wo4.y + n2 * wo4.z + n3 * wo4.w;
      z = wave_sum(z);
      if (lane == 0) {
        z += bout[0];
        if (grow < HALF_N) {
          out[HALF_N + grow] = z;
        } else {
          int jj = grow - HALF_N;
          out[jj] = z;
          out[2 * HALF_N + jj] = z;
        }
      }
    } else {
      float4 o; o.x = n0; o.y = n1; o.z = n2; o.w = n3;
      reinterpret_cast<float4*>(nodes + (size_t)grow * 256)[lane] = o;
      if (grow < HALF_N) {
        float mu = wave_sum(n0 + n1 + n2 + n3) * (1.0f / DIM);
        float d0 = n0 - mu, d1 = n1 - mu, d2 = n2 - mu, d3 = n3 - mu;
        float var = wave_sum(d0*d0 + d1*d1 + d2*d2 + d3*d3) * (1.0f / DIM);
        float rs = rsqrtf(var + 1e-5f);
        float4 gv = reinterpret_cast<const float4*>(ln1g)[lane];
        float4 bv = reinterpret_cast<const float4*>(ln1b)[lane];
        bf16x4 ob;
        ob[0] = (bf16)(d0 * rs * gv.x + bv.x);
        ob[1] = (bf16)(d1 * rs * gv.y + bv.y);
        ob[2] = (bf16)(d2 * rs * gv.z + bv.z);
        ob[3] = (bf16)(d3 * rs * gv.w + bv.w);
        *reinterpret_cast<bf16x4*>(A2 + (size_t)grow * 512 + lane * 4) = ob;
      }
    }
  }
}

// ---------------- ELL build ----------------
__global__ void ell_build(const int* __restrict__ ei, int* __restrict__ deg,
                          int* __restrict__ ell) {
  int e = blockIdx.x * 256 + threadIdx.x;
  if (e >= N_EDGES) return;
  int s = ei[e], d = ei[N_EDGES + e];
  int pos = atomicAdd(&deg[d], 1);
  if (pos < MAXDEG) ell[d * MAXDEG + pos] = s;
}

// ---------------- attention gather (wave per dst, online softmax, bf16) ------
// qkv layout [HALF][1024]: q (0..255) | interleaved k/v (256..767) | eB (768..1023)
__global__ void attn_gather(const int* __restrict__ deg, const int* __restrict__ ell,
                            const bf16* __restrict__ qkv, bf16* __restrict__ agg) {
  int d = blockIdx.x * 4 + (threadIdx.x >> 6);
  if (d >= HALF_N) return;
  int lane = threadIdx.x & 63;
  int cnt = deg[d]; if (cnt > MAXDEG) cnt = MAXDEG;
  const bf16* qr = qkv + (size_t)d * 1024;
  bf16x4 qb = *reinterpret_cast<const bf16x4*>(qr + lane * 4);
  float q0 = (float)qb[0], q1 = (float)qb[1], q2 = (float)qb[2], q3 = (float)qb[3];
  float m = -INFINITY, den = 0.0f, a0 = 0.0f, a1 = 0.0f, a2 = 0.0f, a3 = 0.0f;
  for (int i = 0; i < cnt; ++i) {
    int s = ell[d * MAXDEG + i];
    bf16x8 kv8 = *reinterpret_cast<const bf16x8*>(qkv + (size_t)s * 1024 + 256 + lane * 8);
    float p = q0 * (float)kv8[0] + q1 * (float)kv8[1] +
              q2 * (float)kv8[2] + q3 * (float)kv8[3];
    p += __shfl_xor(p, 1); p += __shfl_xor(p, 2);
    p += __shfl_xor(p, 4); p += __shfl_xor(p, 8);
    float sim = p * 0.125f;
    float nm = fmaxf(m, sim);
    float sc = __expf(m - nm);
    float w  = __expf(sim - nm);
    den = den * sc + w;
    a0 = a0 * sc + w * (float)kv8[4];
    a1 = a1 * sc + w * (float)kv8[5];
    a2 = a2 * sc + w * (float)kv8[6];
    a3 = a3 * sc + w * (float)kv8[7];
    m = nm;
  }
  bf16x4 o;
  if (cnt > 0) {
    float inv = 1.0f / den;
    bf16x4 eb = *reinterpret_cast<const bf16x4*>(qr + 768 + lane * 4);
    o[0] = (bf16)(a0 * inv + (float)eb[0]);
    o[1] = (bf16)(a1 * inv + (float)eb[1]);
    o[2] = (bf16)(a2 * inv + (float)eb[2]);
    o[3] = (bf16)(a3 * inv + (float)eb[3]);
  } else {
    o[0] = (bf16)0.0f; o[1] = (bf16)0.0f; o[2] = (bf16)0.0f; o[3] = (bf16)0.0f;
  }
  *reinterpret_cast<bf16x4*>(agg + (size_t)d * DIM + lane * 4) = o;
}

// ---------------- gated-residual + LN (upper rows: x = fb broadcast) ---------
template<int DO_LN>
__global__ void gr_ln(const float* __restrict__ fb,
                      float* __restrict__ nodes, const float* __restrict__ w,
                      const float* __restrict__ g, const float* __restrict__ b,
                      bf16* __restrict__ xn, int rows) {
  int r = blockIdx.x * 4 + (threadIdx.x >> 6);
  if (r >= rows) return;
  int lane = threadIdx.x & 63;
  float4 f = reinterpret_cast<const float4*>(fb)[lane];
  float x0 = f.x, x1 = f.y, x2 = f.z, x3 = f.w;
  float4 rv = reinterpret_cast<const float4*>(nodes + (size_t)r * DIM)[lane];
  float4 w0 = reinterpret_cast<const float4*>(w)[lane];
  float4 w1 = reinterpret_cast<const float4*>(w + 256)[lane];
  float4 w2 = reinterpret_cast<const float4*>(w + 512)[lane];
  float p = x0 * (w0.x + w2.x) + rv.x * (w1.x - w2.x)
          + x1 * (w0.y + w2.y) + rv.y * (w1.y - w2.y)
          + x2 * (w0.z + w2.z) + rv.z * (w1.z - w2.z)
          + x3 * (w0.w + w2.w) + rv.w * (w1.w - w2.w);
  p = wave_sum(p);
  float gate = 1.0f / (1.0f + __expf(-p));
  float n0 = x0 * gate + rv.x * (1.0f - gate);
  float n1 = x1 * gate + rv.y * (1.0f - gate);
  float n2 = x2 * gate + rv.z * (1.0f - gate);
  float n3 = x3 * gate + rv.w * (1.0f - gate);
  float4 o; o.x = n0; o.y = n1; o.z = n2; o.w = n3;
  reinterpret_cast<float4*>(nodes + (size_t)r * DIM)[lane] = o;
  if (DO_LN) {
    float mu = wave_sum(n0 + n1 + n2 + n3) * (1.0f / DIM);
    float d0 = n0 - mu, d1 = n1 - mu, d2 = n2 - mu, d3 = n3 - mu;
    float var = wave_sum(d0*d0 + d1*d1 + d2*d2 + d3*d3) * (1.0f / DIM);
    float rs = rsqrtf(var + 1e-5f);
    float4 gv = reinterpret_cast<const float4*>(g)[lane];
    float4 bv = reinterpret_cast<const float4*>(b)[lane];
    bf16x4 ob;
    ob[0] = (bf16)(d0 * rs * gv.x + bv.x);
    ob[1] = (bf16)(d1 * rs * gv.y + bv.y);
    ob[2] = (bf16)(d2 * rs * gv.z + bv.z);
    ob[3] = (bf16)(d3 * rs * gv.w + bv.w);
    *reinterpret_cast<bf16x4*>(xn + (size_t)r * DIM + lane * 4) = ob;
  }
}

// ---------------- weight prep: chunk-packed bf16 layouts ----------------
__global__ void prep_w(const float* __restrict__ Wq, const float* __restrict__ Wkv,
                       const float* __restrict__ We, const float* __restrict__ Wo,
                       const float* __restrict__ W1, const float* __restrict__ W2,
                       bf16* __restrict__ wt) {
  int idx = blockIdx.x * 256 + threadIdx.x;
  if (idx >= 2 * WT_LAYER) return;
  int l = idx / WT_LAYER, r = idx % WT_LAYER;
  float v;
  if (r < 524288) {                       // qkve: 8 x [64 k8][128 n][8 e], k/v interleaved
    int jn = r >> 16, t = r & 65535;
    int k8 = t >> 10, u = t & 1023, n = u >> 3, e = u & 7;
    int ncol = jn * 128 + n, k = k8 * 8 + e;
    if (ncol < 256) {
      v = (k < 256) ? Wq[l * 65536 + k * 256 + ncol] : 0.0f;
    } else if (ncol < 768) {
      int u2 = ncol - 256;
      int c = (u2 >> 3) * 4 + (u2 & 3);
      int half = (u2 >> 2) & 1;
      if (k < 256) v = Wkv[l * 131072 + k * 512 + half * 256 + c];
      else         v = We[l * 131072 + (k - 256) * 256 + c];
    } else {
      int c = ncol - 768;
      v = (k < 256) ? 0.0f : We[l * 131072 + k * 256 + c];
    }
  } else if (r < 589824) {                // Wo: 2 x [32 k8][128 n][8 e]
    int rr = r - 524288;
    int jn = rr >> 15, t = rr & 32767;
    int k8 = t >> 10, u = t & 1023, n = u >> 3, e = u & 7;
    v = Wo[l * 65536 + (k8 * 8 + e) * 256 + jn * 128 + n];
  } else if (r < 851968) {                // W1: 8 x [32 k8][128 n][8 e]
    int rr = r - 589824;
    int j = rr >> 15, t = rr & 32767;
    int k8 = t >> 10, u = t & 1023, n = u >> 3, e = u & 7;
    v = W1[l * 262144 + (k8 * 8 + e) * 1024 + j * 128 + n];
  } else {                                // W2: 8 x [16 k8][256 n][8 e]
    int rr = r - 851968;
    int j = rr >> 15, t = rr & 32767;
    int k8 = t >> 11, u = t & 2047, n = u >> 3, e = u & 7;
    v = W2[l * 262144 + (j * 128 + k8 * 8 + e) * 256 + n];
  }
  wt[idx] = (bf16)v;
}

// qkve bias: [2][1024] = [bq | interleaved bk/bv | be]
__global__ void prep_bias(const float* __restrict__ bq, const float* __restrict__ bkv,
                          const float* __restrict__ be, float* __restrict__ biasq) {
  int i = blockIdx.x * 256 + threadIdx.x;
  if (i >= 2048) return;
  int l = i >> 10, n = i & 1023;
  float v;
  if (n < 256) v = bq[l * 256 + n];
  else if (n < 768) {
    int u2 = n - 256;
    int c = (u2 >> 3) * 4 + (u2 & 3);
    int half = (u2 >> 2) & 1;
    v = bkv[l * 512 + half * 256 + c];
  } else v = be[l * 256 + (n - 768)];
  biasq[i] = v;
}

// x (fp32) -> A2 right half (bf16, stride 512)
__global__ void prep_x(const float* __restrict__ x, bf16* __restrict__ A2) {
  int i = blockIdx.x * 256 + threadIdx.x;
  if (i >= HALF_N * 64) return;
  int row = i >> 6, c = i & 63;
  float4 v = reinterpret_cast<const float4*>(x)[i];
  bf16x4 o;
  o[0] = (bf16)v.x; o[1] = (bf16)v.y; o[2] = (bf16)v.z; o[3] = (bf16)v.w;
  *reinterpret_cast<bf16x4*>(A2 + (size_t)row * 512 + 256 + c * 4) = o;
}

extern "C" void kernel_launch(void* const* d_in, const int* in_sizes, int n_in,
                              void* d_out, int out_size, void* d_ws, size_t ws_size,
                              hipStream_t stream) {
  const float* x     = (const float*)d_in[0];
  const int*   ei    = (const int*)d_in[1];
  const float* ln1_g = (const float*)d_in[2];
  const float* ln1_b = (const float*)d_in[3];
  const float* Wq    = (const float*)d_in[4];
  const float* bq    = (const float*)d_in[5];
  const float* Wkv   = (const float*)d_in[6];
  const float* bkv   = (const float*)d_in[7];
  const float* We    = (const float*)d_in[8];
  const float* be    = (const float*)d_in[9];
  const float* Wo    = (const float*)d_in[10];
  const float* bo    = (const float*)d_in[11];
  const float* g_attn= (const float*)d_in[12];
  const float* ln2_g = (const float*)d_in[13];
  const float* ln2_b = (const float*)d_in[14];
  const float* W1    = (const float*)d_in[15];
  const float* b1    = (const float*)d_in[16];
  const float* W2    = (const float*)d_in[17];
  const float* b2    = (const float*)d_in[18];
  const float* g_ff  = (const float*)d_in[19];
  const float* Wout  = (const float*)d_in[20];
  const float* bout  = (const float*)d_in[21];
  float* out = (float*)d_out;

  char* base = (char*)d_ws;
  float* nodes   = (float*)base;  base += (size_t)N_NODES * DIM * 4;      // 51.2 MB
  bf16*  A2      = (bf16*)base;   base += (size_t)HALF_N * 512 * 2;       // 25.6 MB
  bf16*  xn_bf   = (bf16*)base;   base += (size_t)N_NODES * DIM * 2;      // 25.6 MB
  bf16*  qkv     = (bf16*)base;   base += (size_t)HALF_N * 1024 * 2;      // 51.2 MB
  bf16*  agg     = (bf16*)base;   base += (size_t)HALF_N * DIM * 2;       // 12.8 MB
  bf16*  wt      = (bf16*)base;   base += (size_t)2 * WT_LAYER * 2;       // 4.5 MB
  float* biasq   = (float*)base;  base += 2048 * 4;
  int*   deg     = (int*)base;    base += HALF_N * 4;
  int*   ell     = (int*)base;    base += (size_t)HALF_N * MAXDEG * 4;    // 6.4 MB

  // one-time prep
  hipMemcpyAsync(nodes, x, (size_t)N_NODES * DIM * sizeof(float),
                 hipMemcpyDeviceToDevice, stream);
  prep_w<<<(2 * WT_LAYER + 255) / 256, 256, 0, stream>>>(Wq, Wkv, We, Wo, W1, W2, wt);
  prep_bias<<<8, 256, 0, stream>>>(bq, bkv, be, biasq);
  prep_x<<<(HALF_N * 64 + 255) / 256, 256, 0, stream>>>(x, A2);
  hipMemsetAsync(deg, 0, HALF_N * sizeof(int), stream);
  ell_build<<<(N_EDGES + 255) / 256, 256, 0, stream>>>(ei, deg, ell);

  const int GP_H = (HALF_N + 63) / 64;    // 391
  const int GP_N = (N_NODES + 63) / 64;   // 782

  for (int l = 0; l < NDEPTH; ++l) {
    const bf16* wl = wt + (size_t)l * WT_LAYER;
    if (l == 0)
      ln0_kernel<<<(HALF_N + 3) / 4, 256, 0, stream>>>(x, ln1_g, ln1_b, A2);
    // qkv|eB = [xn|x] @ qkveT + bias (k/v interleaved cols)
    gemm_nloop<512, 8><<<GP_H, 256, 0, stream>>>(A2, wl + WT_QKVE, biasq + l * 1024, qkv, HALF_N);
    // attention gather (+eB)
    attn_gather<<<(HALF_N + 3) / 4, 256, 0, stream>>>(deg, ell, qkv, agg);
    // attn_out = agg @ Wo + bo, fused gr1 + LN2 (lower rows)
    wo_fused<<<GP_H, 256, 0, stream>>>(agg, wl + WT_WO, bo + l * DIM,
                                       g_attn + l * 768, ln2_g + l * DIM, ln2_b + l * DIM,
                                       nodes, xn_bf, HALF_N);
    // upper rows: x = bo broadcast, gr1 + LN2
    gr_ln<1><<<(HALF_N + 3) / 4, 256, 0, stream>>>(
        bo + l * DIM, nodes + (size_t)HALF_N * DIM, g_attn + l * 768,
        ln2_g + l * DIM, ln2_b + l * DIM, xn_bf + (size_t)HALF_N * DIM, HALF_N);
    // fused FF + gr2 (+LN1next into A2 | +out-proj)
    if (l < NDEPTH - 1) {
      ff_fused<0><<<GP_N, 512, 0, stream>>>(
          xn_bf, wl + WT_W1, b1 + l * 1024, wl + WT_W2, b2 + l * DIM,
          nodes, g_ff + l * 768, ln1_g + (l + 1) * DIM, ln1_b + (l + 1) * DIM, A2,
          nullptr, nullptr, nullptr, N_NODES);
    } else {
      ff_fused<1><<<GP_N, 512, 0, stream>>>(
          xn_bf, wl + WT_W1, b1 + l * 1024, wl + WT_W2, b2 + l * DIM,
          nodes, g_ff + l * 768, nullptr, nullptr, nullptr,
          Wout, bout, out, N_NODES);
    }
  }
}